// Round 16
// baseline (279.378 us; speedup 1.0000x reference)
//
#include <hip/hip_runtime.h>
#include <hip/hip_bf16.h>
#include <math.h>

// DigitCaps dynamic routing. B=512, I=1152, K=8, C=10, D=16, 3 iters.
//
// Best-known = R21 (250.5 us). Session ledger:
// R5 structure: materialize bf16 u_hat (189 MB) in ws; each routing pass
//   streams it once; softmax fully in-register.
// Producer dead-ends: ILP prefetch folded (R11); forced launch_bounds spills
//   (R7); b-oct spills (R16); sched_barrier pins spilling loads (R17);
//   b-pairs double W_t loads (R12).
// Producer WINS: R15 LDS cross-wave reduce (atomics /4); R21 u-slab staged
//   in LDS (removed 8 unscalarized VMEM/ii): 128 -> 86us, VALUBusy 43->60%.
// Route dead-ends: c-lane >=80 VGPR (R13); 4-wide (R16); global_load_lds
//   staging (R19). route6s ~67us.
// Route WINS: R14 cd-quad TLP (VGPR~20, grid 2048); R18 inline squash.
// R22 (this round): (a) producer pack via __float22bfloat162_rn ->
//   v_cvt_pk_bf16_f32 (saves ~56 VALU/ii of ~150; RNE identical);
//   (b) XCD swizzle wblk=(bid&7)*256+bid/8 on producer+routes: blocks
//   sharing atomic targets (16/bq, 4/b) become XCD-local -> s-line
//   ping-pong eliminated. Bijective (2048%8==0), work-reorder only.

#define UHQ 40          // ushort4 quads per (b,i) row (160 bf16 elems)
#define K1_CH 64        // producer i-chunks (18 i each), 4 b per wave

__device__ __forceinline__ float dot8(const float4 w0, const float4 w1,
                                      const float4 ua, const float4 ub) {
    return w0.x*ua.x + w0.y*ua.y + w0.z*ua.z + w0.w*ua.w
         + w1.x*ub.x + w1.y*ub.y + w1.z*ub.z + w1.w*ub.w;
}

__device__ __forceinline__ unsigned short bf16_rn(float x) {
    unsigned u = __float_as_uint(x);
    u += 0x7FFFu + ((u >> 16) & 1u);
    return (unsigned short)(u >> 16);
}
__device__ __forceinline__ float bf16_to_f(unsigned short h) {
    return __uint_as_float(((unsigned)h) << 16);
}

// quad-local squash: lane q holds 4 of the 16 dims of class c=q>>2; the
// 4 lanes of the quad group hold all 16. ns via shfl_xor{1,2}.
__device__ __forceinline__ float4 squash4(float4 x) {
    float ns = x.x*x.x + x.y*x.y + x.z*x.z + x.w*x.w;
    ns += __shfl_xor(ns, 1);
    ns += __shfl_xor(ns, 2);
    const float sc = ns * __builtin_amdgcn_rcpf((1.0f + ns) * (sqrtf(ns) + 1e-8f));
    return make_float4(x.x*sc, x.y*sc, x.z*sc, x.w*sc);
}

// ---------------- W transpose + s-buffer zeroing ----------------
__global__ void transpose_W(const float4* __restrict__ W4, float4* __restrict__ Wt4,
                            float4* __restrict__ zbuf)
{
    int tid = blockIdx.x * 256 + threadIdx.x;
    if (tid < 61440) zbuf[tid] = make_float4(0.f, 0.f, 0.f, 0.f);
    if (tid >= 1152 * 320) return;
    int i = tid / 320, r = tid - i * 320;
    int q = r >> 3, j = r & 7;
    Wt4[i * 320 + j * 40 + q] = W4[tid];   // read coalesced, scatter within 5 KB row
}

// ---------------- Producer: u-slab LDS + cvt_pk pack + LDS reduce, XCD-swizzled ----------------
// K1_CH 64 -> 18 i/wave, 8192 waves, grid 2048 = 8 blocks/CU (VGPR 64 tier).
// wblk swizzle: the 16 work-blocks sharing a bq (same 4 atomic targets + same
// u slab rows) land on ONE XCD. u (9.2 KB) cooperatively staged in LDS; pack
// via __float22bfloat162_rn (v_cvt_pk_bf16_f32, RNE). Waves 1-3 park pass-0
// acc in LDS, wave 0 alone issues atomics. NO W_t prefetch (R11/R16/R17).
__global__ __launch_bounds__(256, 4)
void produce_uhat_t(const float* __restrict__ u, const float* __restrict__ Wt,
                    unsigned short* __restrict__ uhat_h, float* __restrict__ s0)
{
    const int t = threadIdx.x, lane = t & 63, wv = t >> 6;
    const int bid  = blockIdx.x;
    const int wblk = ((bid & 7) << 8) + (bid >> 3);   // XCD-contiguous work id
    const int gid = wblk * 4 + wv;
    const int bq  = gid / K1_CH;          // 0..127 (same for all 4 waves of a block)
    const int b0  = bq * 4;
    const int q   = lane;
    const bool act = (q < UHQ);

    __shared__ float4 red[480];           // 3 waves x 40 lanes x 4 float4 = 7680 B
    __shared__ float4 uL[576];            // u[b0..b0+4)[iblk0..iblk0+72)[8f] = 9216 B

    const int iblk0 = (wblk & 15) * 72;   // block's i-slab start

    // cooperative stage of the block's u slab (576 float4, 256 threads)
    {
        const float4* u4 = (const float4*)u;          // [512][1152][2] float4
        #pragma unroll
        for (int idx = t; idx < 576; idx += 256) {
            const int bb = idx / 144;                 // 0..3
            const int r  = idx - bb * 144;            // 0..143
            uL[idx] = u4[((size_t)(b0 + bb) * 1152 + iblk0) * 2 + r];
        }
    }
    __syncthreads();

    float4 acc[4];
    #pragma unroll
    for (int bb = 0; bb < 4; ++bb) acc[bb] = make_float4(0.f, 0.f, 0.f, 0.f);

    for (int ii = 0; ii < 18; ++ii) {
        const int il = wv * 18 + ii;      // i - iblk0, 0..71
        const int i  = iblk0 + il;
        float4 w4[8];
        if (act) {
            const float4* wb = (const float4*)(Wt + (size_t)i * 1280);
            #pragma unroll
            for (int j = 0; j < 8; ++j) w4[j] = wb[j * 40 + q];   // 640 B contiguous
        }
        #pragma unroll
        for (int bb = 0; bb < 4; ++bb) {
            const int b = b0 + bb;
            const float4* us = &uL[(bb * 72 + il) * 2];
            const float4 ua = us[0], ub = us[1];   // broadcast ds_read, conflict-free
            if (act) {
                float4 uh;
                uh.x = dot8(w4[0], w4[1], ua, ub);
                uh.y = dot8(w4[2], w4[3], ua, ub);
                uh.z = dot8(w4[4], w4[5], ua, ub);
                uh.w = dot8(w4[6], w4[7], ua, ub);
                acc[bb].x += uh.x; acc[bb].y += uh.y;
                acc[bb].z += uh.z; acc[bb].w += uh.w;
                // RNE pack via native packed cvt (m240: intrinsic, not asm)
                __hip_bfloat162 hlo = __float22bfloat162_rn(make_float2(uh.x, uh.y));
                __hip_bfloat162 hhi = __float22bfloat162_rn(make_float2(uh.z, uh.w));
                uint2 hh;
                hh.x = *reinterpret_cast<unsigned*>(&hlo);
                hh.y = *reinterpret_cast<unsigned*>(&hhi);
                ((uint2*)uhat_h)[((size_t)b * 1152 + i) * UHQ + q] = hh;
            }
        }
    }

    // cross-wave reduction of the pass-0 partial sums
    if (wv > 0 && act) {
        float4* rp = red + ((wv - 1) * 40 + q) * 4;
        rp[0] = acc[0]; rp[1] = acc[1]; rp[2] = acc[2]; rp[3] = acc[3];
    }
    __syncthreads();
    if (wv == 0 && act) {
        #pragma unroll
        for (int w = 0; w < 3; ++w) {
            const float4* rp = red + (w * 40 + q) * 4;
            #pragma unroll
            for (int bb = 0; bb < 4; ++bb) {
                const float4 r = rp[bb];
                acc[bb].x += r.x; acc[bb].y += r.y;
                acc[bb].z += r.z; acc[bb].w += r.w;
            }
        }
#if defined(__HIP_DEVICE_COMPILE__)
        #pragma unroll
        for (int bb = 0; bb < 4; ++bb) {
            float* sp = s0 + (size_t)(b0 + bb) * 160 + q * 4;
            unsafeAtomicAdd(sp + 0, acc[bb].x);
            unsafeAtomicAdd(sp + 1, acc[bb].y);
            unsafeAtomicAdd(sp + 2, acc[bb].z);
            unsafeAtomicAdd(sp + 3, acc[bb].w);
        }
#endif
    }
}

// ---------------- Producer fallback (divergent W, no W_t buffer; R9 geometry) ----------------
__global__ __launch_bounds__(256, 4)
void produce_uhat_div(const float* __restrict__ u, const float* __restrict__ W,
                      unsigned short* __restrict__ uhat_h, float* __restrict__ s0)
{
    const int t = threadIdx.x, lane = t & 63, wv = t >> 6;
    const int gid = blockIdx.x * 4 + wv;
    const int bq  = gid / 32;
    const int ch  = gid - bq * 32;
    const int b0  = bq * 4;
    const int i0  = ch * 36;
    const int q   = lane;
    const bool act = (q < UHQ);

    float4 acc[4];
    #pragma unroll
    for (int bb = 0; bb < 4; ++bb) acc[bb] = make_float4(0.f, 0.f, 0.f, 0.f);

    for (int ii = 0; ii < 36; ++ii) {
        const int i = i0 + ii;
        float4 w4[8];
        if (act) {
            const float4* wp = (const float4*)(W + (size_t)i * 1280 + q * 32);
            #pragma unroll
            for (int j = 0; j < 8; ++j) w4[j] = wp[j];
        }
        #pragma unroll
        for (int bb = 0; bb < 4; ++bb) {
            const int b = b0 + bb;
            const float4* up = (const float4*)(u + ((size_t)b * 1152 + i) * 8);
            const float4 ua = up[0], ub = up[1];
            if (act) {
                float4 uh;
                uh.x = dot8(w4[0], w4[1], ua, ub);
                uh.y = dot8(w4[2], w4[3], ua, ub);
                uh.z = dot8(w4[4], w4[5], ua, ub);
                uh.w = dot8(w4[6], w4[7], ua, ub);
                acc[bb].x += uh.x; acc[bb].y += uh.y;
                acc[bb].z += uh.z; acc[bb].w += uh.w;
                ushort4 h;
                h.x = bf16_rn(uh.x); h.y = bf16_rn(uh.y);
                h.z = bf16_rn(uh.z); h.w = bf16_rn(uh.w);
                ((ushort4*)uhat_h)[((size_t)b * 1152 + i) * UHQ + q] = h;
            }
        }
    }
    if (act) {
#if defined(__HIP_DEVICE_COMPILE__)
        #pragma unroll
        for (int bb = 0; bb < 4; ++bb) {
            float* sp = s0 + (size_t)(b0 + bb) * 160 + q * 4;
            unsafeAtomicAdd(sp + 0, acc[bb].x);
            unsafeAtomicAdd(sp + 1, acc[bb].y);
            unsafeAtomicAdd(sp + 2, acc[bb].z);
            unsafeAtomicAdd(sp + 3, acc[bb].w);
        }
#endif
    }
}

// ---------------- Routing pass v6s: cd-quad + inline squash, XCD-swizzled ----------------
// Wave owns (b, i-chunk); lane q = cd-quad (40/64 active). VGPR ~25 ->
// 8 waves/SIMD; grid 2048 = 8 blocks/CU, one uniform round. wblk swizzle:
// the 4 work-blocks sharing a b (same s-prologue lines + atomic targets)
// land on ONE XCD.
template <int PASS>
__global__ __launch_bounds__(256, 8)
void route6s(const unsigned short* __restrict__ uhat_h,
             const float* __restrict__ s0g, const float* __restrict__ s1g,
             float* __restrict__ sg)
{
    const int t = threadIdx.x, lane = t & 63, wv = t >> 6;
    const int bid  = blockIdx.x;
    const int wblk = ((bid & 7) << 8) + (bid >> 3);   // XCD-contiguous work id
    const int gid = wblk * 4 + wv;
    const int b   = gid >> 4;             // 0..511
    const int ch  = gid & 15;             // 0..15
    const int i0  = ch * 72;
    const int q   = lane;
    const bool act = (q < UHQ);

    // inline squash prologue (once per wave; all lanes run the shfls)
    float4 va;
    {
        float4 x0 = make_float4(0.f, 0.f, 0.f, 0.f);
        if (act) x0 = ((const float4*)s0g)[(size_t)b * UHQ + q];
        x0.x *= 0.1f; x0.y *= 0.1f; x0.z *= 0.1f; x0.w *= 0.1f;
        va = squash4(x0);
        if (PASS == 2) {
            float4 x1 = make_float4(0.f, 0.f, 0.f, 0.f);
            if (act) x1 = ((const float4*)s1g)[(size_t)b * UHQ + q];
            const float4 v1 = squash4(x1);
            va.x += v1.x; va.y += v1.y; va.z += v1.z; va.w += v1.w;
        }
    }
    float4 sacc = make_float4(0.f, 0.f, 0.f, 0.f);

    const ushort4* up = (const ushort4*)uhat_h;

    for (int ii = 0; ii < 72; ii += 2) {
        const size_t qi = ((size_t)b * 1152 + i0 + ii) * UHQ + q;
        float4 uh0 = make_float4(0.f, 0.f, 0.f, 0.f);
        float4 uh1 = make_float4(0.f, 0.f, 0.f, 0.f);
        if (act) {
            const ushort4 h0 = up[qi];
            const ushort4 h1 = up[qi + UHQ];
            uh0.x = bf16_to_f(h0.x); uh0.y = bf16_to_f(h0.y);
            uh0.z = bf16_to_f(h0.z); uh0.w = bf16_to_f(h0.w);
            uh1.x = bf16_to_f(h1.x); uh1.y = bf16_to_f(h1.y);
            uh1.z = bf16_to_f(h1.z); uh1.w = bf16_to_f(h1.w);
        }
        // per-c logit: 4-lane segmented reduction (two independent chains)
        float p0 = uh0.x*va.x + uh0.y*va.y + uh0.z*va.z + uh0.w*va.w;
        float p1 = uh1.x*va.x + uh1.y*va.y + uh1.z*va.z + uh1.w*va.w;
        p0 += __shfl_xor(p0, 1);  p1 += __shfl_xor(p1, 1);
        p0 += __shfl_xor(p0, 2);  p1 += __shfl_xor(p1, 2);
        // softmax, no max-subtraction (|logit| < ~0.5); mask inactive lanes
        const float e0 = act ? __expf(p0) : 0.0f;
        const float e1 = act ? __expf(p1) : 0.0f;
        float s0v = e0, s1v = e1;
        // xor-butterfly over strides 4..32: every lane gets sum over the 10 c-groups
        s0v += __shfl_xor(s0v, 4);   s1v += __shfl_xor(s1v, 4);
        s0v += __shfl_xor(s0v, 8);   s1v += __shfl_xor(s1v, 8);
        s0v += __shfl_xor(s0v, 16);  s1v += __shfl_xor(s1v, 16);
        s0v += __shfl_xor(s0v, 32);  s1v += __shfl_xor(s1v, 32);
        const float c0 = e0 * __builtin_amdgcn_rcpf(s0v);
        const float c1 = e1 * __builtin_amdgcn_rcpf(s1v);
        sacc.x += c0 * uh0.x + c1 * uh1.x;
        sacc.y += c0 * uh0.y + c1 * uh1.y;
        sacc.z += c0 * uh0.z + c1 * uh1.z;
        sacc.w += c0 * uh0.w + c1 * uh1.w;
    }
    if (act) {
#if defined(__HIP_DEVICE_COMPILE__)
        float* sp = sg + (size_t)b * 160 + q * 4;
        unsafeAtomicAdd(sp + 0, sacc.x);
        unsafeAtomicAdd(sp + 1, sacc.y);
        unsafeAtomicAdd(sp + 2, sacc.z);
        unsafeAtomicAdd(sp + 3, sacc.w);
#endif
    }
}

// ---------------- squash with pre-scale (final output only) ----------------
__global__ void squash_scale(const float* __restrict__ s, float* __restrict__ vout,
                             float scale)
{
    int r = blockIdx.x * 256 + threadIdx.x;
    if (r >= 512 * 10) return;
    const float* sp = s + (size_t)r * 16;
    float sv[16];
    float ns = 0.0f;
    #pragma unroll
    for (int d = 0; d < 16; ++d) {
        float x = sp[d] * scale;
        sv[d] = x;
        ns += x * x;
    }
    float sc = ns / ((1.0f + ns) * (sqrtf(ns) + 1e-8f));
    float* o = vout + (size_t)r * 16;
    #pragma unroll
    for (int d = 0; d < 16; ++d) o[d] = sv[d] * sc;
}

// ---------------- tiny-ws fallback (R3-style): thread owns (b,c) ----------------
template <int PASS>
__global__ __launch_bounds__(256, 4)
void pass_fb(const float* __restrict__ u, const float* __restrict__ W,
             const float* __restrict__ v0g, const float* __restrict__ v1g,
             float* __restrict__ s_atomic)
{
    const int t    = threadIdx.x;
    const int lane = t & 63;
    const int wv   = t >> 6;
    const int bsub = lane / 10;
    const int c    = lane - bsub * 10;
    const bool lane_ok = (bsub < 6);
    const int b    = blockIdx.y * 24 + wv * 6 + bsub;
    const bool valid = lane_ok && (b < 512);
    const int bc   = valid ? b : 511;
    const int base = lane_ok ? bsub * 10 : 0;
    const int i0   = blockIdx.x * 24;

    float v[16];
    #pragma unroll
    for (int d = 0; d < 16; ++d) v[d] = 0.0f;
    if (PASS >= 1) {
        const float* vp = v0g + ((size_t)bc * 10 + c) * 16;
        #pragma unroll
        for (int d = 0; d < 16; ++d) v[d] = vp[d];
        if (PASS >= 2) {
            const float* vq = v1g + ((size_t)bc * 10 + c) * 16;
            #pragma unroll
            for (int d = 0; d < 16; ++d) v[d] += vq[d];
        }
    }

    float s_acc[16];
    #pragma unroll
    for (int d = 0; d < 16; ++d) s_acc[d] = 0.0f;

    for (int ii = 0; ii < 24; ++ii) {
        const int i = i0 + ii;
        const float4* up = (const float4*)(u + ((size_t)bc * 1152 + i) * 8);
        const float4 ua = up[0];
        const float4 ub = up[1];
        const float* Wp = W + ((size_t)i * 10 + c) * 128;

        float h[16];
        #pragma unroll
        for (int d = 0; d < 16; ++d) {
            const float4* wp = (const float4*)(Wp + d * 8);
            h[d] = dot8(wp[0], wp[1], ua, ub);
        }

        if (PASS == 0) {
            #pragma unroll
            for (int d = 0; d < 16; ++d) s_acc[d] += h[d];
        } else {
            float lg = 0.0f;
            #pragma unroll
            for (int d = 0; d < 16; ++d) lg += h[d] * v[d];
            float lj[10];
            #pragma unroll
            for (int j = 0; j < 10; ++j) lj[j] = __shfl(lg, base + j);
            float m = lj[0];
            #pragma unroll
            for (int j = 1; j < 10; ++j) m = fmaxf(m, lj[j]);
            float sum = 0.0f;
            #pragma unroll
            for (int j = 0; j < 10; ++j) sum += __expf(lj[j] - m);
            const float coef = __expf(lg - m) / sum;
            #pragma unroll
            for (int d = 0; d < 16; ++d) s_acc[d] += coef * h[d];
        }
    }
    if (PASS == 0) {
        #pragma unroll
        for (int d = 0; d < 16; ++d) s_acc[d] *= 0.1f;
    }
    if (valid) {
#if defined(__HIP_DEVICE_COMPILE__)
        #pragma unroll
        for (int d = 0; d < 16; ++d)
            unsafeAtomicAdd(&s_atomic[((size_t)b * 10 + c) * 16 + d], s_acc[d]);
#endif
    }
}

extern "C" void kernel_launch(void* const* d_in, const int* in_sizes, int n_in,
                              void* d_out, int out_size, void* d_ws, size_t ws_size,
                              hipStream_t stream)
{
    const float* u = (const float*)d_in[0];   // [512,1152,8]
    const float* W = (const float*)d_in[1];   // [1152,10,16,8]
    float* out = (float*)d_out;               // [512,10,16]

    float* v0 = (float*)d_ws;
    float* v1 = v0 + 81920;
    float* s0 = v1 + 81920;
    float* s1 = s0 + 81920;
    float* s2 = s1 + 81920;
    float* wt = s2 + 81920;                   // 1,474,560 f32 (5.9 MB)

    const size_t head   = (size_t)5 * 81920 * sizeof(float);          // 1.64 MB
    const size_t wtsz   = (size_t)1152 * 1280 * sizeof(float);        // 5.90 MB
    const size_t uh_b16 = (size_t)512 * 1152 * 160 * 2;               // 188.7 MB

    dim3 blk(256);

    if (ws_size >= head + wtsz + uh_b16) {
        unsigned short* uhh = (unsigned short*)(wt + 1152 * 1280);
        // transpose_W also zeroes s0..s2 (61440 float4) - no separate memset
        transpose_W<<<1440, blk, 0, stream>>>((const float4*)W, (float4*)wt,
                                              (float4*)s0);
        produce_uhat_t<<<2048, blk, 0, stream>>>(u, wt, uhh, s0);
        route6s<1><<<2048, blk, 0, stream>>>(uhh, s0, nullptr, s1);
        route6s<2><<<2048, blk, 0, stream>>>(uhh, s0, s1, s2);
        squash_scale<<<20, blk, 0, stream>>>(s2, out, 1.0f);
    } else if (ws_size >= head + uh_b16) {
        hipMemsetAsync(s0, 0, (size_t)3 * 81920 * sizeof(float), stream);
        unsigned short* uhh = (unsigned short*)wt;   // no W_t buffer
        produce_uhat_div<<<1024, blk, 0, stream>>>(u, W, uhh, s0);
        route6s<1><<<2048, blk, 0, stream>>>(uhh, s0, nullptr, s1);
        route6s<2><<<2048, blk, 0, stream>>>(uhh, s0, s1, s2);
        squash_scale<<<20, blk, 0, stream>>>(s2, out, 1.0f);
    } else {
        hipMemsetAsync(s0, 0, (size_t)3 * 81920 * sizeof(float), stream);
        dim3 grid(48, 22);
        pass_fb<0><<<grid, blk, 0, stream>>>(u, W, nullptr, nullptr, s0);
        squash_scale<<<20, blk, 0, stream>>>(s0, v0, 1.0f);
        pass_fb<1><<<grid, blk, 0, stream>>>(u, W, v0, nullptr, s1);
        squash_scale<<<20, blk, 0, stream>>>(s1, v1, 1.0f);
        pass_fb<2><<<grid, blk, 0, stream>>>(u, W, v0, v1, s2);
        squash_scale<<<20, blk, 0, stream>>>(s2, out, 1.0f);
    }
}

// Round 18
// 253.815 us; speedup vs baseline: 1.1007x; 1.1007x over previous
//
#include <hip/hip_runtime.h>
#include <hip/hip_bf16.h>
#include <math.h>

// DigitCaps dynamic routing. B=512, I=1152, K=8, C=10, D=16, 3 iters.
//
// Best-known = R21 (250.5 us). Session ledger:
// R5 structure: materialize bf16 u_hat (189 MB) in ws; each routing pass
//   streams it once; softmax fully in-register.
// Producer dead-ends: ILP prefetch folded (R11); forced launch_bounds spills
//   (R7); b-oct spills (R16); sched_barrier pins spilling loads (R17);
//   b-pairs double W_t loads (R12).
// Producer WINS: R15 LDS cross-wave reduce (atomics /4); R21 u-slab staged
//   in LDS (removed 8 unscalarized VMEM/ii): 128 -> 86us, VALUBusy 43->60%.
// Route WINS: R14 cd-quad TLP (VGPR~20, grid 2048); R18 inline squash.
// R22 POST-MORTEM: XCD swizzle destroyed DATA locality (producer FETCH
//   14.5 -> 120 MB, routes +18us each): it made atomic lines (KBs) local
//   while scattering the W_t/u_hat streams (195 MB) across XCDs. REVERTED.
//   cvt_pk pack is FETCH-neutral (pure VALU) - kept for isolated test.
// R24 = R23 resubmitted (R17-round bench died on infra, never measured):
//   R21 verbatim + cvt_pk pack only. Falsifier: if FETCH stays high,
//   pack is implicated -> full R21 revert.

#define UHQ 40          // ushort4 quads per (b,i) row (160 bf16 elems)
#define K1_CH 64        // producer i-chunks (18 i each), 4 b per wave

__device__ __forceinline__ float dot8(const float4 w0, const float4 w1,
                                      const float4 ua, const float4 ub) {
    return w0.x*ua.x + w0.y*ua.y + w0.z*ua.z + w0.w*ua.w
         + w1.x*ub.x + w1.y*ub.y + w1.z*ub.z + w1.w*ub.w;
}

__device__ __forceinline__ unsigned short bf16_rn(float x) {
    unsigned u = __float_as_uint(x);
    u += 0x7FFFu + ((u >> 16) & 1u);
    return (unsigned short)(u >> 16);
}
__device__ __forceinline__ float bf16_to_f(unsigned short h) {
    return __uint_as_float(((unsigned)h) << 16);
}

// quad-local squash: lane q holds 4 of the 16 dims of class c=q>>2; the
// 4 lanes of the quad group hold all 16. ns via shfl_xor{1,2}.
__device__ __forceinline__ float4 squash4(float4 x) {
    float ns = x.x*x.x + x.y*x.y + x.z*x.z + x.w*x.w;
    ns += __shfl_xor(ns, 1);
    ns += __shfl_xor(ns, 2);
    const float sc = ns * __builtin_amdgcn_rcpf((1.0f + ns) * (sqrtf(ns) + 1e-8f));
    return make_float4(x.x*sc, x.y*sc, x.z*sc, x.w*sc);
}

// ---------------- W transpose + s-buffer zeroing ----------------
__global__ void transpose_W(const float4* __restrict__ W4, float4* __restrict__ Wt4,
                            float4* __restrict__ zbuf)
{
    int tid = blockIdx.x * 256 + threadIdx.x;
    if (tid < 61440) zbuf[tid] = make_float4(0.f, 0.f, 0.f, 0.f);
    if (tid >= 1152 * 320) return;
    int i = tid / 320, r = tid - i * 320;
    int q = r >> 3, j = r & 7;
    Wt4[i * 320 + j * 40 + q] = W4[tid];   // read coalesced, scatter within 5 KB row
}

// ---------------- Producer (R21 geometry): u-slab LDS + cvt_pk pack + LDS reduce ----------------
// K1_CH 64 -> 18 i/wave, 8192 waves, grid 2048 = 8 blocks/CU (VGPR 64 tier),
// DEFAULT block mapping (no swizzle - R22 lesson). u (9.2 KB) cooperatively
// staged in LDS; pack via __float22bfloat162_rn (v_cvt_pk_bf16_f32, RNE).
// Waves 1-3 park pass-0 acc in LDS, wave 0 alone issues atomics.
// NO W_t prefetch (R11/R16/R17: folds or spills).
__global__ __launch_bounds__(256, 4)
void produce_uhat_t(const float* __restrict__ u, const float* __restrict__ Wt,
                    unsigned short* __restrict__ uhat_h, float* __restrict__ s0)
{
    const int t = threadIdx.x, lane = t & 63, wv = t >> 6;
    const int gid = blockIdx.x * 4 + wv;
    const int bq  = gid / K1_CH;          // 0..127 (same for all 4 waves of a block)
    const int b0  = bq * 4;
    const int q   = lane;
    const bool act = (q < UHQ);

    __shared__ float4 red[480];           // 3 waves x 40 lanes x 4 float4 = 7680 B
    __shared__ float4 uL[576];            // u[b0..b0+4)[iblk0..iblk0+72)[8f] = 9216 B

    const int iblk0 = (blockIdx.x & 15) * 72;   // block's i-slab start

    // cooperative stage of the block's u slab (576 float4, 256 threads)
    {
        const float4* u4 = (const float4*)u;          // [512][1152][2] float4
        #pragma unroll
        for (int idx = t; idx < 576; idx += 256) {
            const int bb = idx / 144;                 // 0..3
            const int r  = idx - bb * 144;            // 0..143
            uL[idx] = u4[((size_t)(b0 + bb) * 1152 + iblk0) * 2 + r];
        }
    }
    __syncthreads();

    float4 acc[4];
    #pragma unroll
    for (int bb = 0; bb < 4; ++bb) acc[bb] = make_float4(0.f, 0.f, 0.f, 0.f);

    for (int ii = 0; ii < 18; ++ii) {
        const int il = wv * 18 + ii;      // i - iblk0, 0..71
        const int i  = iblk0 + il;
        float4 w4[8];
        if (act) {
            const float4* wb = (const float4*)(Wt + (size_t)i * 1280);
            #pragma unroll
            for (int j = 0; j < 8; ++j) w4[j] = wb[j * 40 + q];   // 640 B contiguous
        }
        #pragma unroll
        for (int bb = 0; bb < 4; ++bb) {
            const int b = b0 + bb;
            const float4* us = &uL[(bb * 72 + il) * 2];
            const float4 ua = us[0], ub = us[1];   // broadcast ds_read, conflict-free
            if (act) {
                float4 uh;
                uh.x = dot8(w4[0], w4[1], ua, ub);
                uh.y = dot8(w4[2], w4[3], ua, ub);
                uh.z = dot8(w4[4], w4[5], ua, ub);
                uh.w = dot8(w4[6], w4[7], ua, ub);
                acc[bb].x += uh.x; acc[bb].y += uh.y;
                acc[bb].z += uh.z; acc[bb].w += uh.w;
                // RNE pack via native packed cvt (m240: intrinsic, not asm)
                __hip_bfloat162 hlo = __float22bfloat162_rn(make_float2(uh.x, uh.y));
                __hip_bfloat162 hhi = __float22bfloat162_rn(make_float2(uh.z, uh.w));
                uint2 hh;
                hh.x = *reinterpret_cast<unsigned*>(&hlo);
                hh.y = *reinterpret_cast<unsigned*>(&hhi);
                ((uint2*)uhat_h)[((size_t)b * 1152 + i) * UHQ + q] = hh;
            }
        }
    }

    // cross-wave reduction of the pass-0 partial sums
    if (wv > 0 && act) {
        float4* rp = red + ((wv - 1) * 40 + q) * 4;
        rp[0] = acc[0]; rp[1] = acc[1]; rp[2] = acc[2]; rp[3] = acc[3];
    }
    __syncthreads();
    if (wv == 0 && act) {
        #pragma unroll
        for (int w = 0; w < 3; ++w) {
            const float4* rp = red + (w * 40 + q) * 4;
            #pragma unroll
            for (int bb = 0; bb < 4; ++bb) {
                const float4 r = rp[bb];
                acc[bb].x += r.x; acc[bb].y += r.y;
                acc[bb].z += r.z; acc[bb].w += r.w;
            }
        }
#if defined(__HIP_DEVICE_COMPILE__)
        #pragma unroll
        for (int bb = 0; bb < 4; ++bb) {
            float* sp = s0 + (size_t)(b0 + bb) * 160 + q * 4;
            unsafeAtomicAdd(sp + 0, acc[bb].x);
            unsafeAtomicAdd(sp + 1, acc[bb].y);
            unsafeAtomicAdd(sp + 2, acc[bb].z);
            unsafeAtomicAdd(sp + 3, acc[bb].w);
        }
#endif
    }
}

// ---------------- Producer fallback (divergent W, no W_t buffer; R9 geometry) ----------------
__global__ __launch_bounds__(256, 4)
void produce_uhat_div(const float* __restrict__ u, const float* __restrict__ W,
                      unsigned short* __restrict__ uhat_h, float* __restrict__ s0)
{
    const int t = threadIdx.x, lane = t & 63, wv = t >> 6;
    const int gid = blockIdx.x * 4 + wv;
    const int bq  = gid / 32;
    const int ch  = gid - bq * 32;
    const int b0  = bq * 4;
    const int i0  = ch * 36;
    const int q   = lane;
    const bool act = (q < UHQ);

    float4 acc[4];
    #pragma unroll
    for (int bb = 0; bb < 4; ++bb) acc[bb] = make_float4(0.f, 0.f, 0.f, 0.f);

    for (int ii = 0; ii < 36; ++ii) {
        const int i = i0 + ii;
        float4 w4[8];
        if (act) {
            const float4* wp = (const float4*)(W + (size_t)i * 1280 + q * 32);
            #pragma unroll
            for (int j = 0; j < 8; ++j) w4[j] = wp[j];
        }
        #pragma unroll
        for (int bb = 0; bb < 4; ++bb) {
            const int b = b0 + bb;
            const float4* up = (const float4*)(u + ((size_t)b * 1152 + i) * 8);
            const float4 ua = up[0], ub = up[1];
            if (act) {
                float4 uh;
                uh.x = dot8(w4[0], w4[1], ua, ub);
                uh.y = dot8(w4[2], w4[3], ua, ub);
                uh.z = dot8(w4[4], w4[5], ua, ub);
                uh.w = dot8(w4[6], w4[7], ua, ub);
                acc[bb].x += uh.x; acc[bb].y += uh.y;
                acc[bb].z += uh.z; acc[bb].w += uh.w;
                ushort4 h;
                h.x = bf16_rn(uh.x); h.y = bf16_rn(uh.y);
                h.z = bf16_rn(uh.z); h.w = bf16_rn(uh.w);
                ((ushort4*)uhat_h)[((size_t)b * 1152 + i) * UHQ + q] = h;
            }
        }
    }
    if (act) {
#if defined(__HIP_DEVICE_COMPILE__)
        #pragma unroll
        for (int bb = 0; bb < 4; ++bb) {
            float* sp = s0 + (size_t)(b0 + bb) * 160 + q * 4;
            unsafeAtomicAdd(sp + 0, acc[bb].x);
            unsafeAtomicAdd(sp + 1, acc[bb].y);
            unsafeAtomicAdd(sp + 2, acc[bb].z);
            unsafeAtomicAdd(sp + 3, acc[bb].w);
        }
#endif
    }
}

// ---------------- Routing pass v6s (R18/R21 WIN config, FROZEN, no swizzle) ----------------
// Wave owns (b, i-chunk); lane q = cd-quad (40/64 active). VGPR ~25 ->
// 8 waves/SIMD; grid 2048 = 8 blocks/CU, one uniform round. v computed
// inline from raw s accumulators (quad-local squash).
template <int PASS>
__global__ __launch_bounds__(256, 8)
void route6s(const unsigned short* __restrict__ uhat_h,
             const float* __restrict__ s0g, const float* __restrict__ s1g,
             float* __restrict__ sg)
{
    const int t = threadIdx.x, lane = t & 63, wv = t >> 6;
    const int gid = blockIdx.x * 4 + wv;
    const int b   = gid >> 4;             // 0..511
    const int ch  = gid & 15;             // 0..15
    const int i0  = ch * 72;
    const int q   = lane;
    const bool act = (q < UHQ);

    // inline squash prologue (once per wave; all lanes run the shfls)
    float4 va;
    {
        float4 x0 = make_float4(0.f, 0.f, 0.f, 0.f);
        if (act) x0 = ((const float4*)s0g)[(size_t)b * UHQ + q];
        x0.x *= 0.1f; x0.y *= 0.1f; x0.z *= 0.1f; x0.w *= 0.1f;
        va = squash4(x0);
        if (PASS == 2) {
            float4 x1 = make_float4(0.f, 0.f, 0.f, 0.f);
            if (act) x1 = ((const float4*)s1g)[(size_t)b * UHQ + q];
            const float4 v1 = squash4(x1);
            va.x += v1.x; va.y += v1.y; va.z += v1.z; va.w += v1.w;
        }
    }
    float4 sacc = make_float4(0.f, 0.f, 0.f, 0.f);

    const ushort4* up = (const ushort4*)uhat_h;

    for (int ii = 0; ii < 72; ii += 2) {
        const size_t qi = ((size_t)b * 1152 + i0 + ii) * UHQ + q;
        float4 uh0 = make_float4(0.f, 0.f, 0.f, 0.f);
        float4 uh1 = make_float4(0.f, 0.f, 0.f, 0.f);
        if (act) {
            const ushort4 h0 = up[qi];
            const ushort4 h1 = up[qi + UHQ];
            uh0.x = bf16_to_f(h0.x); uh0.y = bf16_to_f(h0.y);
            uh0.z = bf16_to_f(h0.z); uh0.w = bf16_to_f(h0.w);
            uh1.x = bf16_to_f(h1.x); uh1.y = bf16_to_f(h1.y);
            uh1.z = bf16_to_f(h1.z); uh1.w = bf16_to_f(h1.w);
        }
        // per-c logit: 4-lane segmented reduction (two independent chains)
        float p0 = uh0.x*va.x + uh0.y*va.y + uh0.z*va.z + uh0.w*va.w;
        float p1 = uh1.x*va.x + uh1.y*va.y + uh1.z*va.z + uh1.w*va.w;
        p0 += __shfl_xor(p0, 1);  p1 += __shfl_xor(p1, 1);
        p0 += __shfl_xor(p0, 2);  p1 += __shfl_xor(p1, 2);
        // softmax, no max-subtraction (|logit| < ~0.5); mask inactive lanes
        const float e0 = act ? __expf(p0) : 0.0f;
        const float e1 = act ? __expf(p1) : 0.0f;
        float s0v = e0, s1v = e1;
        // xor-butterfly over strides 4..32: every lane gets sum over the 10 c-groups
        s0v += __shfl_xor(s0v, 4);   s1v += __shfl_xor(s1v, 4);
        s0v += __shfl_xor(s0v, 8);   s1v += __shfl_xor(s1v, 8);
        s0v += __shfl_xor(s0v, 16);  s1v += __shfl_xor(s1v, 16);
        s0v += __shfl_xor(s0v, 32);  s1v += __shfl_xor(s1v, 32);
        const float c0 = e0 * __builtin_amdgcn_rcpf(s0v);
        const float c1 = e1 * __builtin_amdgcn_rcpf(s1v);
        sacc.x += c0 * uh0.x + c1 * uh1.x;
        sacc.y += c0 * uh0.y + c1 * uh1.y;
        sacc.z += c0 * uh0.z + c1 * uh1.z;
        sacc.w += c0 * uh0.w + c1 * uh1.w;
    }
    if (act) {
#if defined(__HIP_DEVICE_COMPILE__)
        float* sp = sg + (size_t)b * 160 + q * 4;
        unsafeAtomicAdd(sp + 0, sacc.x);
        unsafeAtomicAdd(sp + 1, sacc.y);
        unsafeAtomicAdd(sp + 2, sacc.z);
        unsafeAtomicAdd(sp + 3, sacc.w);
#endif
    }
}

// ---------------- squash with pre-scale (final output only) ----------------
__global__ void squash_scale(const float* __restrict__ s, float* __restrict__ vout,
                             float scale)
{
    int r = blockIdx.x * 256 + threadIdx.x;
    if (r >= 512 * 10) return;
    const float* sp = s + (size_t)r * 16;
    float sv[16];
    float ns = 0.0f;
    #pragma unroll
    for (int d = 0; d < 16; ++d) {
        float x = sp[d] * scale;
        sv[d] = x;
        ns += x * x;
    }
    float sc = ns / ((1.0f + ns) * (sqrtf(ns) + 1e-8f));
    float* o = vout + (size_t)r * 16;
    #pragma unroll
    for (int d = 0; d < 16; ++d) o[d] = sv[d] * sc;
}

// ---------------- tiny-ws fallback (R3-style): thread owns (b,c) ----------------
template <int PASS>
__global__ __launch_bounds__(256, 4)
void pass_fb(const float* __restrict__ u, const float* __restrict__ W,
             const float* __restrict__ v0g, const float* __restrict__ v1g,
             float* __restrict__ s_atomic)
{
    const int t    = threadIdx.x;
    const int lane = t & 63;
    const int wv   = t >> 6;
    const int bsub = lane / 10;
    const int c    = lane - bsub * 10;
    const bool lane_ok = (bsub < 6);
    const int b    = blockIdx.y * 24 + wv * 6 + bsub;
    const bool valid = lane_ok && (b < 512);
    const int bc   = valid ? b : 511;
    const int base = lane_ok ? bsub * 10 : 0;
    const int i0   = blockIdx.x * 24;

    float v[16];
    #pragma unroll
    for (int d = 0; d < 16; ++d) v[d] = 0.0f;
    if (PASS >= 1) {
        const float* vp = v0g + ((size_t)bc * 10 + c) * 16;
        #pragma unroll
        for (int d = 0; d < 16; ++d) v[d] = vp[d];
        if (PASS >= 2) {
            const float* vq = v1g + ((size_t)bc * 10 + c) * 16;
            #pragma unroll
            for (int d = 0; d < 16; ++d) v[d] += vq[d];
        }
    }

    float s_acc[16];
    #pragma unroll
    for (int d = 0; d < 16; ++d) s_acc[d] = 0.0f;

    for (int ii = 0; ii < 24; ++ii) {
        const int i = i0 + ii;
        const float4* up = (const float4*)(u + ((size_t)bc * 1152 + i) * 8);
        const float4 ua = up[0];
        const float4 ub = up[1];
        const float* Wp = W + ((size_t)i * 10 + c) * 128;

        float h[16];
        #pragma unroll
        for (int d = 0; d < 16; ++d) {
            const float4* wp = (const float4*)(Wp + d * 8);
            h[d] = dot8(wp[0], wp[1], ua, ub);
        }

        if (PASS == 0) {
            #pragma unroll
            for (int d = 0; d < 16; ++d) s_acc[d] += h[d];
        } else {
            float lg = 0.0f;
            #pragma unroll
            for (int d = 0; d < 16; ++d) lg += h[d] * v[d];
            float lj[10];
            #pragma unroll
            for (int j = 0; j < 10; ++j) lj[j] = __shfl(lg, base + j);
            float m = lj[0];
            #pragma unroll
            for (int j = 1; j < 10; ++j) m = fmaxf(m, lj[j]);
            float sum = 0.0f;
            #pragma unroll
            for (int j = 0; j < 10; ++j) sum += __expf(lj[j] - m);
            const float coef = __expf(lg - m) / sum;
            #pragma unroll
            for (int d = 0; d < 16; ++d) s_acc[d] += coef * h[d];
        }
    }
    if (PASS == 0) {
        #pragma unroll
        for (int d = 0; d < 16; ++d) s_acc[d] *= 0.1f;
    }
    if (valid) {
#if defined(__HIP_DEVICE_COMPILE__)
        #pragma unroll
        for (int d = 0; d < 16; ++d)
            unsafeAtomicAdd(&s_atomic[((size_t)b * 10 + c) * 16 + d], s_acc[d]);
#endif
    }
}

extern "C" void kernel_launch(void* const* d_in, const int* in_sizes, int n_in,
                              void* d_out, int out_size, void* d_ws, size_t ws_size,
                              hipStream_t stream)
{
    const float* u = (const float*)d_in[0];   // [512,1152,8]
    const float* W = (const float*)d_in[1];   // [1152,10,16,8]
    float* out = (float*)d_out;               // [512,10,16]

    float* v0 = (float*)d_ws;
    float* v1 = v0 + 81920;
    float* s0 = v1 + 81920;
    float* s1 = s0 + 81920;
    float* s2 = s1 + 81920;
    float* wt = s2 + 81920;                   // 1,474,560 f32 (5.9 MB)

    const size_t head   = (size_t)5 * 81920 * sizeof(float);          // 1.64 MB
    const size_t wtsz   = (size_t)1152 * 1280 * sizeof(float);        // 5.90 MB
    const size_t uh_b16 = (size_t)512 * 1152 * 160 * 2;               // 188.7 MB

    dim3 blk(256);

    if (ws_size >= head + wtsz + uh_b16) {
        unsigned short* uhh = (unsigned short*)(wt + 1152 * 1280);
        // transpose_W also zeroes s0..s2 (61440 float4) - no separate memset
        transpose_W<<<1440, blk, 0, stream>>>((const float4*)W, (float4*)wt,
                                              (float4*)s0);
        produce_uhat_t<<<2048, blk, 0, stream>>>(u, wt, uhh, s0);
        route6s<1><<<2048, blk, 0, stream>>>(uhh, s0, nullptr, s1);
        route6s<2><<<2048, blk, 0, stream>>>(uhh, s0, s1, s2);
        squash_scale<<<20, blk, 0, stream>>>(s2, out, 1.0f);
    } else if (ws_size >= head + uh_b16) {
        hipMemsetAsync(s0, 0, (size_t)3 * 81920 * sizeof(float), stream);
        unsigned short* uhh = (unsigned short*)wt;   // no W_t buffer
        produce_uhat_div<<<1024, blk, 0, stream>>>(u, W, uhh, s0);
        route6s<1><<<2048, blk, 0, stream>>>(uhh, s0, nullptr, s1);
        route6s<2><<<2048, blk, 0, stream>>>(uhh, s0, s1, s2);
        squash_scale<<<20, blk, 0, stream>>>(s2, out, 1.0f);
    } else {
        hipMemsetAsync(s0, 0, (size_t)3 * 81920 * sizeof(float), stream);
        dim3 grid(48, 22);
        pass_fb<0><<<grid, blk, 0, stream>>>(u, W, nullptr, nullptr, s0);
        squash_scale<<<20, blk, 0, stream>>>(s0, v0, 1.0f);
        pass_fb<1><<<grid, blk, 0, stream>>>(u, W, v0, nullptr, s1);
        squash_scale<<<20, blk, 0, stream>>>(s1, v1, 1.0f);
        pass_fb<2><<<grid, blk, 0, stream>>>(u, W, v0, v1, s2);
        squash_scale<<<20, blk, 0, stream>>>(s2, out, 1.0f);
    }
}

// Round 19
// 246.671 us; speedup vs baseline: 1.1326x; 1.0290x over previous
//
#include <hip/hip_runtime.h>
#include <hip/hip_bf16.h>
#include <math.h>

// DigitCaps dynamic routing. B=512, I=1152, K=8, C=10, D=16, 3 iters.
//
// Best-known = R21/R24 (250.5 / 253.8 us, same config family, noise ~1.5%).
// R5 structure: materialize bf16 u_hat (189 MB) in ws; each routing pass
//   streams it once; softmax fully in-register.
// Producer dead-ends (FROZEN at R21+pack): ILP prefetch folded (R11); forced
//   launch_bounds spills (R7); b-oct spills (R16); sched_barrier pins
//   spilling loads (R17); b-pairs double W_t loads (R12).
// Producer WINS: R15 LDS cross-wave reduce; R21 u-slab in LDS (128->86us);
//   R24 cvt_pk pack (~2us).
// Route WINS: R14 cd-quad TLP (VGPR~20, grid 2048 = 8 blocks/CU); R18
//   inline squash. Route dead-ends: c-lane (R13), 4-wide batch (R16),
//   global_load_lds staging (R19), XCD swizzle (R22: FETCH x8 blowup).
// R25 (this round): route9 = route6s + 1-step register prefetch rotate
//   (load pair t+1 BEFORE computing pair t). route4 proved the mechanism
//   (+3us) but only at the 4-wave tier; never combined with route6's 8-wave
//   tier. +4 VGPR (~29 total, far under the 64 cliff - no tier risk).
//   Falsifier: neutral => route is DS-pipe-bound (12 ds_bpermute/iter),
//   67us is its equilibrium, config final.

#define UHQ 40          // ushort4 quads per (b,i) row (160 bf16 elems)
#define K1_CH 64        // producer i-chunks (18 i each), 4 b per wave

__device__ __forceinline__ float dot8(const float4 w0, const float4 w1,
                                      const float4 ua, const float4 ub) {
    return w0.x*ua.x + w0.y*ua.y + w0.z*ua.z + w0.w*ua.w
         + w1.x*ub.x + w1.y*ub.y + w1.z*ub.z + w1.w*ub.w;
}

__device__ __forceinline__ unsigned short bf16_rn(float x) {
    unsigned u = __float_as_uint(x);
    u += 0x7FFFu + ((u >> 16) & 1u);
    return (unsigned short)(u >> 16);
}
__device__ __forceinline__ float bf16_to_f(unsigned short h) {
    return __uint_as_float(((unsigned)h) << 16);
}

// quad-local squash: lane q holds 4 of the 16 dims of class c=q>>2; the
// 4 lanes of the quad group hold all 16. ns via shfl_xor{1,2}.
__device__ __forceinline__ float4 squash4(float4 x) {
    float ns = x.x*x.x + x.y*x.y + x.z*x.z + x.w*x.w;
    ns += __shfl_xor(ns, 1);
    ns += __shfl_xor(ns, 2);
    const float sc = ns * __builtin_amdgcn_rcpf((1.0f + ns) * (sqrtf(ns) + 1e-8f));
    return make_float4(x.x*sc, x.y*sc, x.z*sc, x.w*sc);
}

// ---------------- W transpose + s-buffer zeroing ----------------
__global__ void transpose_W(const float4* __restrict__ W4, float4* __restrict__ Wt4,
                            float4* __restrict__ zbuf)
{
    int tid = blockIdx.x * 256 + threadIdx.x;
    if (tid < 61440) zbuf[tid] = make_float4(0.f, 0.f, 0.f, 0.f);
    if (tid >= 1152 * 320) return;
    int i = tid / 320, r = tid - i * 320;
    int q = r >> 3, j = r & 7;
    Wt4[i * 320 + j * 40 + q] = W4[tid];   // read coalesced, scatter within 5 KB row
}

// ---------------- Producer (FROZEN R21+pack): u-slab LDS + cvt_pk + LDS reduce ----------------
// K1_CH 64 -> 18 i/wave, 8192 waves, grid 2048 = 8 blocks/CU (VGPR 64 tier),
// DEFAULT block mapping (no swizzle - R22). u (9.2 KB) cooperatively staged
// in LDS; pack via __float22bfloat162_rn. Waves 1-3 park pass-0 acc in LDS,
// wave 0 alone issues atomics. NO W_t prefetch (R11/R16/R17).
__global__ __launch_bounds__(256, 4)
void produce_uhat_t(const float* __restrict__ u, const float* __restrict__ Wt,
                    unsigned short* __restrict__ uhat_h, float* __restrict__ s0)
{
    const int t = threadIdx.x, lane = t & 63, wv = t >> 6;
    const int gid = blockIdx.x * 4 + wv;
    const int bq  = gid / K1_CH;          // 0..127 (same for all 4 waves of a block)
    const int b0  = bq * 4;
    const int q   = lane;
    const bool act = (q < UHQ);

    __shared__ float4 red[480];           // 3 waves x 40 lanes x 4 float4 = 7680 B
    __shared__ float4 uL[576];            // u[b0..b0+4)[iblk0..iblk0+72)[8f] = 9216 B

    const int iblk0 = (blockIdx.x & 15) * 72;   // block's i-slab start

    // cooperative stage of the block's u slab (576 float4, 256 threads)
    {
        const float4* u4 = (const float4*)u;          // [512][1152][2] float4
        #pragma unroll
        for (int idx = t; idx < 576; idx += 256) {
            const int bb = idx / 144;                 // 0..3
            const int r  = idx - bb * 144;            // 0..143
            uL[idx] = u4[((size_t)(b0 + bb) * 1152 + iblk0) * 2 + r];
        }
    }
    __syncthreads();

    float4 acc[4];
    #pragma unroll
    for (int bb = 0; bb < 4; ++bb) acc[bb] = make_float4(0.f, 0.f, 0.f, 0.f);

    for (int ii = 0; ii < 18; ++ii) {
        const int il = wv * 18 + ii;      // i - iblk0, 0..71
        const int i  = iblk0 + il;
        float4 w4[8];
        if (act) {
            const float4* wb = (const float4*)(Wt + (size_t)i * 1280);
            #pragma unroll
            for (int j = 0; j < 8; ++j) w4[j] = wb[j * 40 + q];   // 640 B contiguous
        }
        #pragma unroll
        for (int bb = 0; bb < 4; ++bb) {
            const int b = b0 + bb;
            const float4* us = &uL[(bb * 72 + il) * 2];
            const float4 ua = us[0], ub = us[1];   // broadcast ds_read, conflict-free
            if (act) {
                float4 uh;
                uh.x = dot8(w4[0], w4[1], ua, ub);
                uh.y = dot8(w4[2], w4[3], ua, ub);
                uh.z = dot8(w4[4], w4[5], ua, ub);
                uh.w = dot8(w4[6], w4[7], ua, ub);
                acc[bb].x += uh.x; acc[bb].y += uh.y;
                acc[bb].z += uh.z; acc[bb].w += uh.w;
                // RNE pack via native packed cvt (m240: intrinsic, not asm)
                __hip_bfloat162 hlo = __float22bfloat162_rn(make_float2(uh.x, uh.y));
                __hip_bfloat162 hhi = __float22bfloat162_rn(make_float2(uh.z, uh.w));
                uint2 hh;
                hh.x = *reinterpret_cast<unsigned*>(&hlo);
                hh.y = *reinterpret_cast<unsigned*>(&hhi);
                ((uint2*)uhat_h)[((size_t)b * 1152 + i) * UHQ + q] = hh;
            }
        }
    }

    // cross-wave reduction of the pass-0 partial sums
    if (wv > 0 && act) {
        float4* rp = red + ((wv - 1) * 40 + q) * 4;
        rp[0] = acc[0]; rp[1] = acc[1]; rp[2] = acc[2]; rp[3] = acc[3];
    }
    __syncthreads();
    if (wv == 0 && act) {
        #pragma unroll
        for (int w = 0; w < 3; ++w) {
            const float4* rp = red + (w * 40 + q) * 4;
            #pragma unroll
            for (int bb = 0; bb < 4; ++bb) {
                const float4 r = rp[bb];
                acc[bb].x += r.x; acc[bb].y += r.y;
                acc[bb].z += r.z; acc[bb].w += r.w;
            }
        }
#if defined(__HIP_DEVICE_COMPILE__)
        #pragma unroll
        for (int bb = 0; bb < 4; ++bb) {
            float* sp = s0 + (size_t)(b0 + bb) * 160 + q * 4;
            unsafeAtomicAdd(sp + 0, acc[bb].x);
            unsafeAtomicAdd(sp + 1, acc[bb].y);
            unsafeAtomicAdd(sp + 2, acc[bb].z);
            unsafeAtomicAdd(sp + 3, acc[bb].w);
        }
#endif
    }
}

// ---------------- Producer fallback (divergent W, no W_t buffer; R9 geometry) ----------------
__global__ __launch_bounds__(256, 4)
void produce_uhat_div(const float* __restrict__ u, const float* __restrict__ W,
                      unsigned short* __restrict__ uhat_h, float* __restrict__ s0)
{
    const int t = threadIdx.x, lane = t & 63, wv = t >> 6;
    const int gid = blockIdx.x * 4 + wv;
    const int bq  = gid / 32;
    const int ch  = gid - bq * 32;
    const int b0  = bq * 4;
    const int i0  = ch * 36;
    const int q   = lane;
    const bool act = (q < UHQ);

    float4 acc[4];
    #pragma unroll
    for (int bb = 0; bb < 4; ++bb) acc[bb] = make_float4(0.f, 0.f, 0.f, 0.f);

    for (int ii = 0; ii < 36; ++ii) {
        const int i = i0 + ii;
        float4 w4[8];
        if (act) {
            const float4* wp = (const float4*)(W + (size_t)i * 1280 + q * 32);
            #pragma unroll
            for (int j = 0; j < 8; ++j) w4[j] = wp[j];
        }
        #pragma unroll
        for (int bb = 0; bb < 4; ++bb) {
            const int b = b0 + bb;
            const float4* up = (const float4*)(u + ((size_t)b * 1152 + i) * 8);
            const float4 ua = up[0], ub = up[1];
            if (act) {
                float4 uh;
                uh.x = dot8(w4[0], w4[1], ua, ub);
                uh.y = dot8(w4[2], w4[3], ua, ub);
                uh.z = dot8(w4[4], w4[5], ua, ub);
                uh.w = dot8(w4[6], w4[7], ua, ub);
                acc[bb].x += uh.x; acc[bb].y += uh.y;
                acc[bb].z += uh.z; acc[bb].w += uh.w;
                ushort4 h;
                h.x = bf16_rn(uh.x); h.y = bf16_rn(uh.y);
                h.z = bf16_rn(uh.z); h.w = bf16_rn(uh.w);
                ((ushort4*)uhat_h)[((size_t)b * 1152 + i) * UHQ + q] = h;
            }
        }
    }
    if (act) {
#if defined(__HIP_DEVICE_COMPILE__)
        #pragma unroll
        for (int bb = 0; bb < 4; ++bb) {
            float* sp = s0 + (size_t)(b0 + bb) * 160 + q * 4;
            unsafeAtomicAdd(sp + 0, acc[bb].x);
            unsafeAtomicAdd(sp + 1, acc[bb].y);
            unsafeAtomicAdd(sp + 2, acc[bb].z);
            unsafeAtomicAdd(sp + 3, acc[bb].w);
        }
#endif
    }
}

// ---------------- Routing pass v9: cd-quad + inline squash + 1-step prefetch ----------------
// Wave owns (b, i-chunk); lane q = cd-quad (40/64 active). VGPR ~29 ->
// still the 8-waves/SIMD tier; grid 2048 = 8 blocks/CU, one uniform round.
// Load pair t+1 issued BEFORE computing pair t (route4's mechanism, now at
// route6's occupancy). v computed inline from raw s (quad-local squash).
template <int PASS>
__global__ __launch_bounds__(256, 8)
void route9(const unsigned short* __restrict__ uhat_h,
            const float* __restrict__ s0g, const float* __restrict__ s1g,
            float* __restrict__ sg)
{
    const int t = threadIdx.x, lane = t & 63, wv = t >> 6;
    const int gid = blockIdx.x * 4 + wv;
    const int b   = gid >> 4;             // 0..511
    const int ch  = gid & 15;             // 0..15
    const int i0  = ch * 72;
    const int q   = lane;
    const bool act = (q < UHQ);

    // inline squash prologue (once per wave; all lanes run the shfls)
    float4 va;
    {
        float4 x0 = make_float4(0.f, 0.f, 0.f, 0.f);
        if (act) x0 = ((const float4*)s0g)[(size_t)b * UHQ + q];
        x0.x *= 0.1f; x0.y *= 0.1f; x0.z *= 0.1f; x0.w *= 0.1f;
        va = squash4(x0);
        if (PASS == 2) {
            float4 x1 = make_float4(0.f, 0.f, 0.f, 0.f);
            if (act) x1 = ((const float4*)s1g)[(size_t)b * UHQ + q];
            const float4 v1 = squash4(x1);
            va.x += v1.x; va.y += v1.y; va.z += v1.z; va.w += v1.w;
        }
    }
    float4 sacc = make_float4(0.f, 0.f, 0.f, 0.f);

    const ushort4* up = (const ushort4*)uhat_h;
    size_t qi = ((size_t)b * 1152 + i0) * UHQ + q;

    // preload pair 0
    ushort4 h0 = make_ushort4(0, 0, 0, 0), h1 = h0;
    if (act) { h0 = up[qi]; h1 = up[qi + UHQ]; }

    #pragma unroll 1
    for (int ii = 0; ii < 72; ii += 2) {
        // prefetch next pair before consuming the current one
        ushort4 n0 = make_ushort4(0, 0, 0, 0), n1 = n0;
        if (act && (ii + 2 < 72)) {
            n0 = up[qi + 2 * UHQ];
            n1 = up[qi + 3 * UHQ];
        }
        qi += 2 * UHQ;

        float4 uh0 = make_float4(0.f, 0.f, 0.f, 0.f);
        float4 uh1 = make_float4(0.f, 0.f, 0.f, 0.f);
        uh0.x = bf16_to_f(h0.x); uh0.y = bf16_to_f(h0.y);
        uh0.z = bf16_to_f(h0.z); uh0.w = bf16_to_f(h0.w);
        uh1.x = bf16_to_f(h1.x); uh1.y = bf16_to_f(h1.y);
        uh1.z = bf16_to_f(h1.z); uh1.w = bf16_to_f(h1.w);
        // per-c logit: 4-lane segmented reduction (two independent chains)
        float p0 = uh0.x*va.x + uh0.y*va.y + uh0.z*va.z + uh0.w*va.w;
        float p1 = uh1.x*va.x + uh1.y*va.y + uh1.z*va.z + uh1.w*va.w;
        p0 += __shfl_xor(p0, 1);  p1 += __shfl_xor(p1, 1);
        p0 += __shfl_xor(p0, 2);  p1 += __shfl_xor(p1, 2);
        // softmax, no max-subtraction (|logit| < ~0.5); mask inactive lanes
        const float e0 = act ? __expf(p0) : 0.0f;
        const float e1 = act ? __expf(p1) : 0.0f;
        float s0v = e0, s1v = e1;
        // xor-butterfly over strides 4..32: every lane gets sum over the 10 c-groups
        s0v += __shfl_xor(s0v, 4);   s1v += __shfl_xor(s1v, 4);
        s0v += __shfl_xor(s0v, 8);   s1v += __shfl_xor(s1v, 8);
        s0v += __shfl_xor(s0v, 16);  s1v += __shfl_xor(s1v, 16);
        s0v += __shfl_xor(s0v, 32);  s1v += __shfl_xor(s1v, 32);
        const float c0 = e0 * __builtin_amdgcn_rcpf(s0v);
        const float c1 = e1 * __builtin_amdgcn_rcpf(s1v);
        sacc.x += c0 * uh0.x + c1 * uh1.x;
        sacc.y += c0 * uh0.y + c1 * uh1.y;
        sacc.z += c0 * uh0.z + c1 * uh1.z;
        sacc.w += c0 * uh0.w + c1 * uh1.w;

        h0 = n0; h1 = n1;
    }
    if (act) {
#if defined(__HIP_DEVICE_COMPILE__)
        float* sp = sg + (size_t)b * 160 + q * 4;
        unsafeAtomicAdd(sp + 0, sacc.x);
        unsafeAtomicAdd(sp + 1, sacc.y);
        unsafeAtomicAdd(sp + 2, sacc.z);
        unsafeAtomicAdd(sp + 3, sacc.w);
#endif
    }
}

// ---------------- squash with pre-scale (final output only) ----------------
__global__ void squash_scale(const float* __restrict__ s, float* __restrict__ vout,
                             float scale)
{
    int r = blockIdx.x * 256 + threadIdx.x;
    if (r >= 512 * 10) return;
    const float* sp = s + (size_t)r * 16;
    float sv[16];
    float ns = 0.0f;
    #pragma unroll
    for (int d = 0; d < 16; ++d) {
        float x = sp[d] * scale;
        sv[d] = x;
        ns += x * x;
    }
    float sc = ns / ((1.0f + ns) * (sqrtf(ns) + 1e-8f));
    float* o = vout + (size_t)r * 16;
    #pragma unroll
    for (int d = 0; d < 16; ++d) o[d] = sv[d] * sc;
}

// ---------------- tiny-ws fallback (R3-style): thread owns (b,c) ----------------
template <int PASS>
__global__ __launch_bounds__(256, 4)
void pass_fb(const float* __restrict__ u, const float* __restrict__ W,
             const float* __restrict__ v0g, const float* __restrict__ v1g,
             float* __restrict__ s_atomic)
{
    const int t    = threadIdx.x;
    const int lane = t & 63;
    const int wv   = t >> 6;
    const int bsub = lane / 10;
    const int c    = lane - bsub * 10;
    const bool lane_ok = (bsub < 6);
    const int b    = blockIdx.y * 24 + wv * 6 + bsub;
    const bool valid = lane_ok && (b < 512);
    const int bc   = valid ? b : 511;
    const int base = lane_ok ? bsub * 10 : 0;
    const int i0   = blockIdx.x * 24;

    float v[16];
    #pragma unroll
    for (int d = 0; d < 16; ++d) v[d] = 0.0f;
    if (PASS >= 1) {
        const float* vp = v0g + ((size_t)bc * 10 + c) * 16;
        #pragma unroll
        for (int d = 0; d < 16; ++d) v[d] = vp[d];
        if (PASS >= 2) {
            const float* vq = v1g + ((size_t)bc * 10 + c) * 16;
            #pragma unroll
            for (int d = 0; d < 16; ++d) v[d] += vq[d];
        }
    }

    float s_acc[16];
    #pragma unroll
    for (int d = 0; d < 16; ++d) s_acc[d] = 0.0f;

    for (int ii = 0; ii < 24; ++ii) {
        const int i = i0 + ii;
        const float4* up = (const float4*)(u + ((size_t)bc * 1152 + i) * 8);
        const float4 ua = up[0];
        const float4 ub = up[1];
        const float* Wp = W + ((size_t)i * 10 + c) * 128;

        float h[16];
        #pragma unroll
        for (int d = 0; d < 16; ++d) {
            const float4* wp = (const float4*)(Wp + d * 8);
            h[d] = dot8(wp[0], wp[1], ua, ub);
        }

        if (PASS == 0) {
            #pragma unroll
            for (int d = 0; d < 16; ++d) s_acc[d] += h[d];
        } else {
            float lg = 0.0f;
            #pragma unroll
            for (int d = 0; d < 16; ++d) lg += h[d] * v[d];
            float lj[10];
            #pragma unroll
            for (int j = 0; j < 10; ++j) lj[j] = __shfl(lg, base + j);
            float m = lj[0];
            #pragma unroll
            for (int j = 1; j < 10; ++j) m = fmaxf(m, lj[j]);
            float sum = 0.0f;
            #pragma unroll
            for (int j = 0; j < 10; ++j) sum += __expf(lj[j] - m);
            const float coef = __expf(lg - m) / sum;
            #pragma unroll
            for (int d = 0; d < 16; ++d) s_acc[d] += coef * h[d];
        }
    }
    if (PASS == 0) {
        #pragma unroll
        for (int d = 0; d < 16; ++d) s_acc[d] *= 0.1f;
    }
    if (valid) {
#if defined(__HIP_DEVICE_COMPILE__)
        #pragma unroll
        for (int d = 0; d < 16; ++d)
            unsafeAtomicAdd(&s_atomic[((size_t)b * 10 + c) * 16 + d], s_acc[d]);
#endif
    }
}

extern "C" void kernel_launch(void* const* d_in, const int* in_sizes, int n_in,
                              void* d_out, int out_size, void* d_ws, size_t ws_size,
                              hipStream_t stream)
{
    const float* u = (const float*)d_in[0];   // [512,1152,8]
    const float* W = (const float*)d_in[1];   // [1152,10,16,8]
    float* out = (float*)d_out;               // [512,10,16]

    float* v0 = (float*)d_ws;
    float* v1 = v0 + 81920;
    float* s0 = v1 + 81920;
    float* s1 = s0 + 81920;
    float* s2 = s1 + 81920;
    float* wt = s2 + 81920;                   // 1,474,560 f32 (5.9 MB)

    const size_t head   = (size_t)5 * 81920 * sizeof(float);          // 1.64 MB
    const size_t wtsz   = (size_t)1152 * 1280 * sizeof(float);        // 5.90 MB
    const size_t uh_b16 = (size_t)512 * 1152 * 160 * 2;               // 188.7 MB

    dim3 blk(256);

    if (ws_size >= head + wtsz + uh_b16) {
        unsigned short* uhh = (unsigned short*)(wt + 1152 * 1280);
        // transpose_W also zeroes s0..s2 (61440 float4) - no separate memset
        transpose_W<<<1440, blk, 0, stream>>>((const float4*)W, (float4*)wt,
                                              (float4*)s0);
        produce_uhat_t<<<2048, blk, 0, stream>>>(u, wt, uhh, s0);
        route9<1><<<2048, blk, 0, stream>>>(uhh, s0, nullptr, s1);
        route9<2><<<2048, blk, 0, stream>>>(uhh, s0, s1, s2);
        squash_scale<<<20, blk, 0, stream>>>(s2, out, 1.0f);
    } else if (ws_size >= head + uh_b16) {
        hipMemsetAsync(s0, 0, (size_t)3 * 81920 * sizeof(float), stream);
        unsigned short* uhh = (unsigned short*)wt;   // no W_t buffer
        produce_uhat_div<<<1024, blk, 0, stream>>>(u, W, uhh, s0);
        route9<1><<<2048, blk, 0, stream>>>(uhh, s0, nullptr, s1);
        route9<2><<<2048, blk, 0, stream>>>(uhh, s0, s1, s2);
        squash_scale<<<20, blk, 0, stream>>>(s2, out, 1.0f);
    } else {
        hipMemsetAsync(s0, 0, (size_t)3 * 81920 * sizeof(float), stream);
        dim3 grid(48, 22);
        pass_fb<0><<<grid, blk, 0, stream>>>(u, W, nullptr, nullptr, s0);
        squash_scale<<<20, blk, 0, stream>>>(s0, v0, 1.0f);
        pass_fb<1><<<grid, blk, 0, stream>>>(u, W, v0, nullptr, s1);
        squash_scale<<<20, blk, 0, stream>>>(s1, v1, 1.0f);
        pass_fb<2><<<grid, blk, 0, stream>>>(u, W, v0, v1, s2);
        squash_scale<<<20, blk, 0, stream>>>(s2, out, 1.0f);
    }
}

// Round 20
// 231.763 us; speedup vs baseline: 1.2054x; 1.0643x over previous
//
#include <hip/hip_runtime.h>
#include <hip/hip_bf16.h>
#include <math.h>

// DigitCaps dynamic routing. B=512, I=1152, K=8, C=10, D=16, 3 iters.
//
// Best-known = R25 (246.7 us). Session ledger:
// R5 structure: materialize bf16 u_hat (189 MB) in ws; each routing pass
//   streams it once; softmax fully in-register.
// Producer (FROZEN): R15 LDS cross-wave reduce; R21 u-slab in LDS
//   (128->86us); R24 cvt_pk pack. Dead-ends: ILP prefetch folded (R11),
//   forced launch_bounds spills (R7), b-oct spills (R16), sched_barrier
//   pins spilling loads (R17), b-pairs double W_t loads (R12).
// Route: R14 cd-quad TLP (grid 2048 = 8 blocks/CU); R18 inline squash;
//   R25 1-step prefetch rotate (+3.5us/pass). Dead-ends: c-lane (R13),
//   4-wide batch (R16), global_load_lds staging (R19), XCD swizzle (R22).
// R26 (this round): route10 = route9 + cross-wave LDS atomic reduction.
//   The 4 waves of a route block share the same b (b = gid>>4) and thus
//   the same 160 atomic targets -> waves 1-3 park sacc in LDS (1.9 KB),
//   wave 0 sums + issues the only atomics (per-b contention 16 -> 4
//   wave-sets, atomic instrs /4). Mirrors R15's proven producer win.
//   Falsifier: neutral => route atomics fully overlapped; config final.

#define UHQ 40          // ushort4 quads per (b,i) row (160 bf16 elems)
#define K1_CH 64        // producer i-chunks (18 i each), 4 b per wave

__device__ __forceinline__ float dot8(const float4 w0, const float4 w1,
                                      const float4 ua, const float4 ub) {
    return w0.x*ua.x + w0.y*ua.y + w0.z*ua.z + w0.w*ua.w
         + w1.x*ub.x + w1.y*ub.y + w1.z*ub.z + w1.w*ub.w;
}

__device__ __forceinline__ unsigned short bf16_rn(float x) {
    unsigned u = __float_as_uint(x);
    u += 0x7FFFu + ((u >> 16) & 1u);
    return (unsigned short)(u >> 16);
}
__device__ __forceinline__ float bf16_to_f(unsigned short h) {
    return __uint_as_float(((unsigned)h) << 16);
}

// quad-local squash: lane q holds 4 of the 16 dims of class c=q>>2; the
// 4 lanes of the quad group hold all 16. ns via shfl_xor{1,2}.
__device__ __forceinline__ float4 squash4(float4 x) {
    float ns = x.x*x.x + x.y*x.y + x.z*x.z + x.w*x.w;
    ns += __shfl_xor(ns, 1);
    ns += __shfl_xor(ns, 2);
    const float sc = ns * __builtin_amdgcn_rcpf((1.0f + ns) * (sqrtf(ns) + 1e-8f));
    return make_float4(x.x*sc, x.y*sc, x.z*sc, x.w*sc);
}

// ---------------- W transpose + s-buffer zeroing ----------------
__global__ void transpose_W(const float4* __restrict__ W4, float4* __restrict__ Wt4,
                            float4* __restrict__ zbuf)
{
    int tid = blockIdx.x * 256 + threadIdx.x;
    if (tid < 61440) zbuf[tid] = make_float4(0.f, 0.f, 0.f, 0.f);
    if (tid >= 1152 * 320) return;
    int i = tid / 320, r = tid - i * 320;
    int q = r >> 3, j = r & 7;
    Wt4[i * 320 + j * 40 + q] = W4[tid];   // read coalesced, scatter within 5 KB row
}

// ---------------- Producer (FROZEN R21+pack): u-slab LDS + cvt_pk + LDS reduce ----------------
// K1_CH 64 -> 18 i/wave, 8192 waves, grid 2048 = 8 blocks/CU (VGPR 64 tier),
// DEFAULT block mapping (no swizzle - R22). u (9.2 KB) cooperatively staged
// in LDS; pack via __float22bfloat162_rn. Waves 1-3 park pass-0 acc in LDS,
// wave 0 alone issues atomics. NO W_t prefetch (R11/R16/R17).
__global__ __launch_bounds__(256, 4)
void produce_uhat_t(const float* __restrict__ u, const float* __restrict__ Wt,
                    unsigned short* __restrict__ uhat_h, float* __restrict__ s0)
{
    const int t = threadIdx.x, lane = t & 63, wv = t >> 6;
    const int gid = blockIdx.x * 4 + wv;
    const int bq  = gid / K1_CH;          // 0..127 (same for all 4 waves of a block)
    const int b0  = bq * 4;
    const int q   = lane;
    const bool act = (q < UHQ);

    __shared__ float4 red[480];           // 3 waves x 40 lanes x 4 float4 = 7680 B
    __shared__ float4 uL[576];            // u[b0..b0+4)[iblk0..iblk0+72)[8f] = 9216 B

    const int iblk0 = (blockIdx.x & 15) * 72;   // block's i-slab start

    // cooperative stage of the block's u slab (576 float4, 256 threads)
    {
        const float4* u4 = (const float4*)u;          // [512][1152][2] float4
        #pragma unroll
        for (int idx = t; idx < 576; idx += 256) {
            const int bb = idx / 144;                 // 0..3
            const int r  = idx - bb * 144;            // 0..143
            uL[idx] = u4[((size_t)(b0 + bb) * 1152 + iblk0) * 2 + r];
        }
    }
    __syncthreads();

    float4 acc[4];
    #pragma unroll
    for (int bb = 0; bb < 4; ++bb) acc[bb] = make_float4(0.f, 0.f, 0.f, 0.f);

    for (int ii = 0; ii < 18; ++ii) {
        const int il = wv * 18 + ii;      // i - iblk0, 0..71
        const int i  = iblk0 + il;
        float4 w4[8];
        if (act) {
            const float4* wb = (const float4*)(Wt + (size_t)i * 1280);
            #pragma unroll
            for (int j = 0; j < 8; ++j) w4[j] = wb[j * 40 + q];   // 640 B contiguous
        }
        #pragma unroll
        for (int bb = 0; bb < 4; ++bb) {
            const int b = b0 + bb;
            const float4* us = &uL[(bb * 72 + il) * 2];
            const float4 ua = us[0], ub = us[1];   // broadcast ds_read, conflict-free
            if (act) {
                float4 uh;
                uh.x = dot8(w4[0], w4[1], ua, ub);
                uh.y = dot8(w4[2], w4[3], ua, ub);
                uh.z = dot8(w4[4], w4[5], ua, ub);
                uh.w = dot8(w4[6], w4[7], ua, ub);
                acc[bb].x += uh.x; acc[bb].y += uh.y;
                acc[bb].z += uh.z; acc[bb].w += uh.w;
                // RNE pack via native packed cvt (m240: intrinsic, not asm)
                __hip_bfloat162 hlo = __float22bfloat162_rn(make_float2(uh.x, uh.y));
                __hip_bfloat162 hhi = __float22bfloat162_rn(make_float2(uh.z, uh.w));
                uint2 hh;
                hh.x = *reinterpret_cast<unsigned*>(&hlo);
                hh.y = *reinterpret_cast<unsigned*>(&hhi);
                ((uint2*)uhat_h)[((size_t)b * 1152 + i) * UHQ + q] = hh;
            }
        }
    }

    // cross-wave reduction of the pass-0 partial sums
    if (wv > 0 && act) {
        float4* rp = red + ((wv - 1) * 40 + q) * 4;
        rp[0] = acc[0]; rp[1] = acc[1]; rp[2] = acc[2]; rp[3] = acc[3];
    }
    __syncthreads();
    if (wv == 0 && act) {
        #pragma unroll
        for (int w = 0; w < 3; ++w) {
            const float4* rp = red + (w * 40 + q) * 4;
            #pragma unroll
            for (int bb = 0; bb < 4; ++bb) {
                const float4 r = rp[bb];
                acc[bb].x += r.x; acc[bb].y += r.y;
                acc[bb].z += r.z; acc[bb].w += r.w;
            }
        }
#if defined(__HIP_DEVICE_COMPILE__)
        #pragma unroll
        for (int bb = 0; bb < 4; ++bb) {
            float* sp = s0 + (size_t)(b0 + bb) * 160 + q * 4;
            unsafeAtomicAdd(sp + 0, acc[bb].x);
            unsafeAtomicAdd(sp + 1, acc[bb].y);
            unsafeAtomicAdd(sp + 2, acc[bb].z);
            unsafeAtomicAdd(sp + 3, acc[bb].w);
        }
#endif
    }
}

// ---------------- Producer fallback (divergent W, no W_t buffer; R9 geometry) ----------------
__global__ __launch_bounds__(256, 4)
void produce_uhat_div(const float* __restrict__ u, const float* __restrict__ W,
                      unsigned short* __restrict__ uhat_h, float* __restrict__ s0)
{
    const int t = threadIdx.x, lane = t & 63, wv = t >> 6;
    const int gid = blockIdx.x * 4 + wv;
    const int bq  = gid / 32;
    const int ch  = gid - bq * 32;
    const int b0  = bq * 4;
    const int i0  = ch * 36;
    const int q   = lane;
    const bool act = (q < UHQ);

    float4 acc[4];
    #pragma unroll
    for (int bb = 0; bb < 4; ++bb) acc[bb] = make_float4(0.f, 0.f, 0.f, 0.f);

    for (int ii = 0; ii < 36; ++ii) {
        const int i = i0 + ii;
        float4 w4[8];
        if (act) {
            const float4* wp = (const float4*)(W + (size_t)i * 1280 + q * 32);
            #pragma unroll
            for (int j = 0; j < 8; ++j) w4[j] = wp[j];
        }
        #pragma unroll
        for (int bb = 0; bb < 4; ++bb) {
            const int b = b0 + bb;
            const float4* up = (const float4*)(u + ((size_t)b * 1152 + i) * 8);
            const float4 ua = up[0], ub = up[1];
            if (act) {
                float4 uh;
                uh.x = dot8(w4[0], w4[1], ua, ub);
                uh.y = dot8(w4[2], w4[3], ua, ub);
                uh.z = dot8(w4[4], w4[5], ua, ub);
                uh.w = dot8(w4[6], w4[7], ua, ub);
                acc[bb].x += uh.x; acc[bb].y += uh.y;
                acc[bb].z += uh.z; acc[bb].w += uh.w;
                ushort4 h;
                h.x = bf16_rn(uh.x); h.y = bf16_rn(uh.y);
                h.z = bf16_rn(uh.z); h.w = bf16_rn(uh.w);
                ((ushort4*)uhat_h)[((size_t)b * 1152 + i) * UHQ + q] = h;
            }
        }
    }
    if (act) {
#if defined(__HIP_DEVICE_COMPILE__)
        #pragma unroll
        for (int bb = 0; bb < 4; ++bb) {
            float* sp = s0 + (size_t)(b0 + bb) * 160 + q * 4;
            unsafeAtomicAdd(sp + 0, acc[bb].x);
            unsafeAtomicAdd(sp + 1, acc[bb].y);
            unsafeAtomicAdd(sp + 2, acc[bb].z);
            unsafeAtomicAdd(sp + 3, acc[bb].w);
        }
#endif
    }
}

// ---------------- Routing pass v10: cd-quad + inline squash + prefetch + LDS atomic reduce ----------------
// Wave owns (b, i-chunk); lane q = cd-quad (40/64 active). The block's 4
// waves share b (b = gid>>4; block gids differ only in bits 0-1) -> their
// sacc target the SAME 160 floats: waves 1-3 park sacc in LDS, wave 0 sums
// and issues the only atomics (per-b atomic sets 16 -> 4). VGPR ~30, grid
// 2048 = 8 blocks/CU, one uniform round.
template <int PASS>
__global__ __launch_bounds__(256, 8)
void route10(const unsigned short* __restrict__ uhat_h,
             const float* __restrict__ s0g, const float* __restrict__ s1g,
             float* __restrict__ sg)
{
    const int t = threadIdx.x, lane = t & 63, wv = t >> 6;
    const int gid = blockIdx.x * 4 + wv;
    const int b   = gid >> 4;             // 0..511 (same for block's 4 waves)
    const int ch  = gid & 15;             // 0..15 (distinct per wave)
    const int i0  = ch * 72;
    const int q   = lane;
    const bool act = (q < UHQ);

    __shared__ float4 red[120];           // 3 waves x 40 lanes x float4 = 1920 B

    // inline squash prologue (once per wave; all lanes run the shfls)
    float4 va;
    {
        float4 x0 = make_float4(0.f, 0.f, 0.f, 0.f);
        if (act) x0 = ((const float4*)s0g)[(size_t)b * UHQ + q];
        x0.x *= 0.1f; x0.y *= 0.1f; x0.z *= 0.1f; x0.w *= 0.1f;
        va = squash4(x0);
        if (PASS == 2) {
            float4 x1 = make_float4(0.f, 0.f, 0.f, 0.f);
            if (act) x1 = ((const float4*)s1g)[(size_t)b * UHQ + q];
            const float4 v1 = squash4(x1);
            va.x += v1.x; va.y += v1.y; va.z += v1.z; va.w += v1.w;
        }
    }
    float4 sacc = make_float4(0.f, 0.f, 0.f, 0.f);

    const ushort4* up = (const ushort4*)uhat_h;
    size_t qi = ((size_t)b * 1152 + i0) * UHQ + q;

    // preload pair 0
    ushort4 h0 = make_ushort4(0, 0, 0, 0), h1 = h0;
    if (act) { h0 = up[qi]; h1 = up[qi + UHQ]; }

    #pragma unroll 1
    for (int ii = 0; ii < 72; ii += 2) {
        // prefetch next pair before consuming the current one
        ushort4 n0 = make_ushort4(0, 0, 0, 0), n1 = n0;
        if (act && (ii + 2 < 72)) {
            n0 = up[qi + 2 * UHQ];
            n1 = up[qi + 3 * UHQ];
        }
        qi += 2 * UHQ;

        float4 uh0 = make_float4(0.f, 0.f, 0.f, 0.f);
        float4 uh1 = make_float4(0.f, 0.f, 0.f, 0.f);
        uh0.x = bf16_to_f(h0.x); uh0.y = bf16_to_f(h0.y);
        uh0.z = bf16_to_f(h0.z); uh0.w = bf16_to_f(h0.w);
        uh1.x = bf16_to_f(h1.x); uh1.y = bf16_to_f(h1.y);
        uh1.z = bf16_to_f(h1.z); uh1.w = bf16_to_f(h1.w);
        // per-c logit: 4-lane segmented reduction (two independent chains)
        float p0 = uh0.x*va.x + uh0.y*va.y + uh0.z*va.z + uh0.w*va.w;
        float p1 = uh1.x*va.x + uh1.y*va.y + uh1.z*va.z + uh1.w*va.w;
        p0 += __shfl_xor(p0, 1);  p1 += __shfl_xor(p1, 1);
        p0 += __shfl_xor(p0, 2);  p1 += __shfl_xor(p1, 2);
        // softmax, no max-subtraction (|logit| < ~0.5); mask inactive lanes
        const float e0 = act ? __expf(p0) : 0.0f;
        const float e1 = act ? __expf(p1) : 0.0f;
        float s0v = e0, s1v = e1;
        // xor-butterfly over strides 4..32: every lane gets sum over the 10 c-groups
        s0v += __shfl_xor(s0v, 4);   s1v += __shfl_xor(s1v, 4);
        s0v += __shfl_xor(s0v, 8);   s1v += __shfl_xor(s1v, 8);
        s0v += __shfl_xor(s0v, 16);  s1v += __shfl_xor(s1v, 16);
        s0v += __shfl_xor(s0v, 32);  s1v += __shfl_xor(s1v, 32);
        const float c0 = e0 * __builtin_amdgcn_rcpf(s0v);
        const float c1 = e1 * __builtin_amdgcn_rcpf(s1v);
        sacc.x += c0 * uh0.x + c1 * uh1.x;
        sacc.y += c0 * uh0.y + c1 * uh1.y;
        sacc.z += c0 * uh0.z + c1 * uh1.z;
        sacc.w += c0 * uh0.w + c1 * uh1.w;

        h0 = n0; h1 = n1;
    }

    // cross-wave reduction: block's 4 waves share b -> same atomic targets
    if (wv > 0 && act) red[(wv - 1) * 40 + q] = sacc;
    __syncthreads();
    if (wv == 0 && act) {
        #pragma unroll
        for (int w = 0; w < 3; ++w) {
            const float4 r = red[w * 40 + q];
            sacc.x += r.x; sacc.y += r.y; sacc.z += r.z; sacc.w += r.w;
        }
#if defined(__HIP_DEVICE_COMPILE__)
        float* sp = sg + (size_t)b * 160 + q * 4;
        unsafeAtomicAdd(sp + 0, sacc.x);
        unsafeAtomicAdd(sp + 1, sacc.y);
        unsafeAtomicAdd(sp + 2, sacc.z);
        unsafeAtomicAdd(sp + 3, sacc.w);
#endif
    }
}

// ---------------- squash with pre-scale (final output only) ----------------
__global__ void squash_scale(const float* __restrict__ s, float* __restrict__ vout,
                             float scale)
{
    int r = blockIdx.x * 256 + threadIdx.x;
    if (r >= 512 * 10) return;
    const float* sp = s + (size_t)r * 16;
    float sv[16];
    float ns = 0.0f;
    #pragma unroll
    for (int d = 0; d < 16; ++d) {
        float x = sp[d] * scale;
        sv[d] = x;
        ns += x * x;
    }
    float sc = ns / ((1.0f + ns) * (sqrtf(ns) + 1e-8f));
    float* o = vout + (size_t)r * 16;
    #pragma unroll
    for (int d = 0; d < 16; ++d) o[d] = sv[d] * sc;
}

// ---------------- tiny-ws fallback (R3-style): thread owns (b,c) ----------------
template <int PASS>
__global__ __launch_bounds__(256, 4)
void pass_fb(const float* __restrict__ u, const float* __restrict__ W,
             const float* __restrict__ v0g, const float* __restrict__ v1g,
             float* __restrict__ s_atomic)
{
    const int t    = threadIdx.x;
    const int lane = t & 63;
    const int wv   = t >> 6;
    const int bsub = lane / 10;
    const int c    = lane - bsub * 10;
    const bool lane_ok = (bsub < 6);
    const int b    = blockIdx.y * 24 + wv * 6 + bsub;
    const bool valid = lane_ok && (b < 512);
    const int bc   = valid ? b : 511;
    const int base = lane_ok ? bsub * 10 : 0;
    const int i0   = blockIdx.x * 24;

    float v[16];
    #pragma unroll
    for (int d = 0; d < 16; ++d) v[d] = 0.0f;
    if (PASS >= 1) {
        const float* vp = v0g + ((size_t)bc * 10 + c) * 16;
        #pragma unroll
        for (int d = 0; d < 16; ++d) v[d] = vp[d];
        if (PASS >= 2) {
            const float* vq = v1g + ((size_t)bc * 10 + c) * 16;
            #pragma unroll
            for (int d = 0; d < 16; ++d) v[d] += vq[d];
        }
    }

    float s_acc[16];
    #pragma unroll
    for (int d = 0; d < 16; ++d) s_acc[d] = 0.0f;

    for (int ii = 0; ii < 24; ++ii) {
        const int i = i0 + ii;
        const float4* up = (const float4*)(u + ((size_t)bc * 1152 + i) * 8);
        const float4 ua = up[0];
        const float4 ub = up[1];
        const float* Wp = W + ((size_t)i * 10 + c) * 128;

        float h[16];
        #pragma unroll
        for (int d = 0; d < 16; ++d) {
            const float4* wp = (const float4*)(Wp + d * 8);
            h[d] = dot8(wp[0], wp[1], ua, ub);
        }

        if (PASS == 0) {
            #pragma unroll
            for (int d = 0; d < 16; ++d) s_acc[d] += h[d];
        } else {
            float lg = 0.0f;
            #pragma unroll
            for (int d = 0; d < 16; ++d) lg += h[d] * v[d];
            float lj[10];
            #pragma unroll
            for (int j = 0; j < 10; ++j) lj[j] = __shfl(lg, base + j);
            float m = lj[0];
            #pragma unroll
            for (int j = 1; j < 10; ++j) m = fmaxf(m, lj[j]);
            float sum = 0.0f;
            #pragma unroll
            for (int j = 0; j < 10; ++j) sum += __expf(lj[j] - m);
            const float coef = __expf(lg - m) / sum;
            #pragma unroll
            for (int d = 0; d < 16; ++d) s_acc[d] += coef * h[d];
        }
    }
    if (PASS == 0) {
        #pragma unroll
        for (int d = 0; d < 16; ++d) s_acc[d] *= 0.1f;
    }
    if (valid) {
#if defined(__HIP_DEVICE_COMPILE__)
        #pragma unroll
        for (int d = 0; d < 16; ++d)
            unsafeAtomicAdd(&s_atomic[((size_t)b * 10 + c) * 16 + d], s_acc[d]);
#endif
    }
}

extern "C" void kernel_launch(void* const* d_in, const int* in_sizes, int n_in,
                              void* d_out, int out_size, void* d_ws, size_t ws_size,
                              hipStream_t stream)
{
    const float* u = (const float*)d_in[0];   // [512,1152,8]
    const float* W = (const float*)d_in[1];   // [1152,10,16,8]
    float* out = (float*)d_out;               // [512,10,16]

    float* v0 = (float*)d_ws;
    float* v1 = v0 + 81920;
    float* s0 = v1 + 81920;
    float* s1 = s0 + 81920;
    float* s2 = s1 + 81920;
    float* wt = s2 + 81920;                   // 1,474,560 f32 (5.9 MB)

    const size_t head   = (size_t)5 * 81920 * sizeof(float);          // 1.64 MB
    const size_t wtsz   = (size_t)1152 * 1280 * sizeof(float);        // 5.90 MB
    const size_t uh_b16 = (size_t)512 * 1152 * 160 * 2;               // 188.7 MB

    dim3 blk(256);

    if (ws_size >= head + wtsz + uh_b16) {
        unsigned short* uhh = (unsigned short*)(wt + 1152 * 1280);
        // transpose_W also zeroes s0..s2 (61440 float4) - no separate memset
        transpose_W<<<1440, blk, 0, stream>>>((const float4*)W, (float4*)wt,
                                              (float4*)s0);
        produce_uhat_t<<<2048, blk, 0, stream>>>(u, wt, uhh, s0);
        route10<1><<<2048, blk, 0, stream>>>(uhh, s0, nullptr, s1);
        route10<2><<<2048, blk, 0, stream>>>(uhh, s0, s1, s2);
        squash_scale<<<20, blk, 0, stream>>>(s2, out, 1.0f);
    } else if (ws_size >= head + uh_b16) {
        hipMemsetAsync(s0, 0, (size_t)3 * 81920 * sizeof(float), stream);
        unsigned short* uhh = (unsigned short*)wt;   // no W_t buffer
        produce_uhat_div<<<1024, blk, 0, stream>>>(u, W, uhh, s0);
        route10<1><<<2048, blk, 0, stream>>>(uhh, s0, nullptr, s1);
        route10<2><<<2048, blk, 0, stream>>>(uhh, s0, s1, s2);
        squash_scale<<<20, blk, 0, stream>>>(s2, out, 1.0f);
    } else {
        hipMemsetAsync(s0, 0, (size_t)3 * 81920 * sizeof(float), stream);
        dim3 grid(48, 22);
        pass_fb<0><<<grid, blk, 0, stream>>>(u, W, nullptr, nullptr, s0);
        squash_scale<<<20, blk, 0, stream>>>(s0, v0, 1.0f);
        pass_fb<1><<<grid, blk, 0, stream>>>(u, W, v0, nullptr, s1);
        squash_scale<<<20, blk, 0, stream>>>(s1, v1, 1.0f);
        pass_fb<2><<<grid, blk, 0, stream>>>(u, W, v0, v1, s2);
        squash_scale<<<20, blk, 0, stream>>>(s2, out, 1.0f);
    }
}

// Round 21
// 223.408 us; speedup vs baseline: 1.2505x; 1.0374x over previous
//
#include <hip/hip_runtime.h>
#include <hip/hip_bf16.h>
#include <math.h>

// DigitCaps dynamic routing. B=512, I=1152, K=8, C=10, D=16, 3 iters.
//
// Best-known = R26 (231.8 us). Session ledger:
// R5 structure: materialize bf16 u_hat (189 MB) in ws; each routing pass
//   streams it once; softmax fully in-register.
// Producer (FROZEN, ~83us): R15 LDS cross-wave reduce; R21 u-slab in LDS
//   (128->86us); R24 cvt_pk pack. Dead-ends: ILP prefetch folded (R11),
//   forced launch_bounds spills (R7), b-oct spills (R16), sched_barrier
//   pins spilling loads (R17), b-pairs double W_t loads (R12).
// Route (~55us/pass): R14 cd-quad TLP (grid 2048 = 8 blocks/CU, the HW
//   occupancy cap); R18 inline squash; R25 1-step prefetch (+3.5us/pass);
//   R26 cross-wave LDS atomic reduce (+7us/pass; per-b atomic sets 16->4).
//   Dead-ends: c-lane (R13), 4-wide batch (R16), global_load_lds staging
//   (R19), XCD swizzle (R22: FETCH x8 blowup).
// R27 (this round): route11 = route10 + 2-DEEP prefetch rotate (4 loads in
//   flight vs 2; extends R25's proven mechanism). +8 VGPR (~38, far under
//   the 64 cliff). Falsifier: neutral => route at DS/VALU equilibrium,
//   declare config final.

#define UHQ 40          // ushort4 quads per (b,i) row (160 bf16 elems)
#define K1_CH 64        // producer i-chunks (18 i each), 4 b per wave

__device__ __forceinline__ float dot8(const float4 w0, const float4 w1,
                                      const float4 ua, const float4 ub) {
    return w0.x*ua.x + w0.y*ua.y + w0.z*ua.z + w0.w*ua.w
         + w1.x*ub.x + w1.y*ub.y + w1.z*ub.z + w1.w*ub.w;
}

__device__ __forceinline__ unsigned short bf16_rn(float x) {
    unsigned u = __float_as_uint(x);
    u += 0x7FFFu + ((u >> 16) & 1u);
    return (unsigned short)(u >> 16);
}
__device__ __forceinline__ float bf16_to_f(unsigned short h) {
    return __uint_as_float(((unsigned)h) << 16);
}

// quad-local squash: lane q holds 4 of the 16 dims of class c=q>>2; the
// 4 lanes of the quad group hold all 16. ns via shfl_xor{1,2}.
__device__ __forceinline__ float4 squash4(float4 x) {
    float ns = x.x*x.x + x.y*x.y + x.z*x.z + x.w*x.w;
    ns += __shfl_xor(ns, 1);
    ns += __shfl_xor(ns, 2);
    const float sc = ns * __builtin_amdgcn_rcpf((1.0f + ns) * (sqrtf(ns) + 1e-8f));
    return make_float4(x.x*sc, x.y*sc, x.z*sc, x.w*sc);
}

// ---------------- W transpose + s-buffer zeroing ----------------
__global__ void transpose_W(const float4* __restrict__ W4, float4* __restrict__ Wt4,
                            float4* __restrict__ zbuf)
{
    int tid = blockIdx.x * 256 + threadIdx.x;
    if (tid < 61440) zbuf[tid] = make_float4(0.f, 0.f, 0.f, 0.f);
    if (tid >= 1152 * 320) return;
    int i = tid / 320, r = tid - i * 320;
    int q = r >> 3, j = r & 7;
    Wt4[i * 320 + j * 40 + q] = W4[tid];   // read coalesced, scatter within 5 KB row
}

// ---------------- Producer (FROZEN R21+pack): u-slab LDS + cvt_pk + LDS reduce ----------------
// K1_CH 64 -> 18 i/wave, 8192 waves, grid 2048 = 8 blocks/CU (VGPR 64 tier),
// DEFAULT block mapping (no swizzle - R22). u (9.2 KB) cooperatively staged
// in LDS; pack via __float22bfloat162_rn. Waves 1-3 park pass-0 acc in LDS,
// wave 0 alone issues atomics. NO W_t prefetch (R11/R16/R17).
__global__ __launch_bounds__(256, 4)
void produce_uhat_t(const float* __restrict__ u, const float* __restrict__ Wt,
                    unsigned short* __restrict__ uhat_h, float* __restrict__ s0)
{
    const int t = threadIdx.x, lane = t & 63, wv = t >> 6;
    const int gid = blockIdx.x * 4 + wv;
    const int bq  = gid / K1_CH;          // 0..127 (same for all 4 waves of a block)
    const int b0  = bq * 4;
    const int q   = lane;
    const bool act = (q < UHQ);

    __shared__ float4 red[480];           // 3 waves x 40 lanes x 4 float4 = 7680 B
    __shared__ float4 uL[576];            // u[b0..b0+4)[iblk0..iblk0+72)[8f] = 9216 B

    const int iblk0 = (blockIdx.x & 15) * 72;   // block's i-slab start

    // cooperative stage of the block's u slab (576 float4, 256 threads)
    {
        const float4* u4 = (const float4*)u;          // [512][1152][2] float4
        #pragma unroll
        for (int idx = t; idx < 576; idx += 256) {
            const int bb = idx / 144;                 // 0..3
            const int r  = idx - bb * 144;            // 0..143
            uL[idx] = u4[((size_t)(b0 + bb) * 1152 + iblk0) * 2 + r];
        }
    }
    __syncthreads();

    float4 acc[4];
    #pragma unroll
    for (int bb = 0; bb < 4; ++bb) acc[bb] = make_float4(0.f, 0.f, 0.f, 0.f);

    for (int ii = 0; ii < 18; ++ii) {
        const int il = wv * 18 + ii;      // i - iblk0, 0..71
        const int i  = iblk0 + il;
        float4 w4[8];
        if (act) {
            const float4* wb = (const float4*)(Wt + (size_t)i * 1280);
            #pragma unroll
            for (int j = 0; j < 8; ++j) w4[j] = wb[j * 40 + q];   // 640 B contiguous
        }
        #pragma unroll
        for (int bb = 0; bb < 4; ++bb) {
            const int b = b0 + bb;
            const float4* us = &uL[(bb * 72 + il) * 2];
            const float4 ua = us[0], ub = us[1];   // broadcast ds_read, conflict-free
            if (act) {
                float4 uh;
                uh.x = dot8(w4[0], w4[1], ua, ub);
                uh.y = dot8(w4[2], w4[3], ua, ub);
                uh.z = dot8(w4[4], w4[5], ua, ub);
                uh.w = dot8(w4[6], w4[7], ua, ub);
                acc[bb].x += uh.x; acc[bb].y += uh.y;
                acc[bb].z += uh.z; acc[bb].w += uh.w;
                // RNE pack via native packed cvt (m240: intrinsic, not asm)
                __hip_bfloat162 hlo = __float22bfloat162_rn(make_float2(uh.x, uh.y));
                __hip_bfloat162 hhi = __float22bfloat162_rn(make_float2(uh.z, uh.w));
                uint2 hh;
                hh.x = *reinterpret_cast<unsigned*>(&hlo);
                hh.y = *reinterpret_cast<unsigned*>(&hhi);
                ((uint2*)uhat_h)[((size_t)b * 1152 + i) * UHQ + q] = hh;
            }
        }
    }

    // cross-wave reduction of the pass-0 partial sums
    if (wv > 0 && act) {
        float4* rp = red + ((wv - 1) * 40 + q) * 4;
        rp[0] = acc[0]; rp[1] = acc[1]; rp[2] = acc[2]; rp[3] = acc[3];
    }
    __syncthreads();
    if (wv == 0 && act) {
        #pragma unroll
        for (int w = 0; w < 3; ++w) {
            const float4* rp = red + (w * 40 + q) * 4;
            #pragma unroll
            for (int bb = 0; bb < 4; ++bb) {
                const float4 r = rp[bb];
                acc[bb].x += r.x; acc[bb].y += r.y;
                acc[bb].z += r.z; acc[bb].w += r.w;
            }
        }
#if defined(__HIP_DEVICE_COMPILE__)
        #pragma unroll
        for (int bb = 0; bb < 4; ++bb) {
            float* sp = s0 + (size_t)(b0 + bb) * 160 + q * 4;
            unsafeAtomicAdd(sp + 0, acc[bb].x);
            unsafeAtomicAdd(sp + 1, acc[bb].y);
            unsafeAtomicAdd(sp + 2, acc[bb].z);
            unsafeAtomicAdd(sp + 3, acc[bb].w);
        }
#endif
    }
}

// ---------------- Producer fallback (divergent W, no W_t buffer; R9 geometry) ----------------
__global__ __launch_bounds__(256, 4)
void produce_uhat_div(const float* __restrict__ u, const float* __restrict__ W,
                      unsigned short* __restrict__ uhat_h, float* __restrict__ s0)
{
    const int t = threadIdx.x, lane = t & 63, wv = t >> 6;
    const int gid = blockIdx.x * 4 + wv;
    const int bq  = gid / 32;
    const int ch  = gid - bq * 32;
    const int b0  = bq * 4;
    const int i0  = ch * 36;
    const int q   = lane;
    const bool act = (q < UHQ);

    float4 acc[4];
    #pragma unroll
    for (int bb = 0; bb < 4; ++bb) acc[bb] = make_float4(0.f, 0.f, 0.f, 0.f);

    for (int ii = 0; ii < 36; ++ii) {
        const int i = i0 + ii;
        float4 w4[8];
        if (act) {
            const float4* wp = (const float4*)(W + (size_t)i * 1280 + q * 32);
            #pragma unroll
            for (int j = 0; j < 8; ++j) w4[j] = wp[j];
        }
        #pragma unroll
        for (int bb = 0; bb < 4; ++bb) {
            const int b = b0 + bb;
            const float4* up = (const float4*)(u + ((size_t)b * 1152 + i) * 8);
            const float4 ua = up[0], ub = up[1];
            if (act) {
                float4 uh;
                uh.x = dot8(w4[0], w4[1], ua, ub);
                uh.y = dot8(w4[2], w4[3], ua, ub);
                uh.z = dot8(w4[4], w4[5], ua, ub);
                uh.w = dot8(w4[6], w4[7], ua, ub);
                acc[bb].x += uh.x; acc[bb].y += uh.y;
                acc[bb].z += uh.z; acc[bb].w += uh.w;
                ushort4 h;
                h.x = bf16_rn(uh.x); h.y = bf16_rn(uh.y);
                h.z = bf16_rn(uh.z); h.w = bf16_rn(uh.w);
                ((ushort4*)uhat_h)[((size_t)b * 1152 + i) * UHQ + q] = h;
            }
        }
    }
    if (act) {
#if defined(__HIP_DEVICE_COMPILE__)
        #pragma unroll
        for (int bb = 0; bb < 4; ++bb) {
            float* sp = s0 + (size_t)(b0 + bb) * 160 + q * 4;
            unsafeAtomicAdd(sp + 0, acc[bb].x);
            unsafeAtomicAdd(sp + 1, acc[bb].y);
            unsafeAtomicAdd(sp + 2, acc[bb].z);
            unsafeAtomicAdd(sp + 3, acc[bb].w);
        }
#endif
    }
}

// ---------------- Routing pass v11: route10 + 2-deep prefetch rotate ----------------
// Wave owns (b, i-chunk); lane q = cd-quad (40/64 active). 4 loads in
// flight (pairs t+1, t+2) while computing pair t. Block's 4 waves share b:
// waves 1-3 park sacc in LDS, wave 0 sums + issues the only atomics.
// VGPR ~38 (<64 cliff), grid 2048 = 8 blocks/CU, one uniform round.
template <int PASS>
__global__ __launch_bounds__(256, 8)
void route11(const unsigned short* __restrict__ uhat_h,
             const float* __restrict__ s0g, const float* __restrict__ s1g,
             float* __restrict__ sg)
{
    const int t = threadIdx.x, lane = t & 63, wv = t >> 6;
    const int gid = blockIdx.x * 4 + wv;
    const int b   = gid >> 4;             // 0..511 (same for block's 4 waves)
    const int ch  = gid & 15;             // 0..15 (distinct per wave)
    const int i0  = ch * 72;
    const int q   = lane;
    const bool act = (q < UHQ);

    __shared__ float4 red[120];           // 3 waves x 40 lanes x float4 = 1920 B

    // inline squash prologue (once per wave; all lanes run the shfls)
    float4 va;
    {
        float4 x0 = make_float4(0.f, 0.f, 0.f, 0.f);
        if (act) x0 = ((const float4*)s0g)[(size_t)b * UHQ + q];
        x0.x *= 0.1f; x0.y *= 0.1f; x0.z *= 0.1f; x0.w *= 0.1f;
        va = squash4(x0);
        if (PASS == 2) {
            float4 x1 = make_float4(0.f, 0.f, 0.f, 0.f);
            if (act) x1 = ((const float4*)s1g)[(size_t)b * UHQ + q];
            const float4 v1 = squash4(x1);
            va.x += v1.x; va.y += v1.y; va.z += v1.z; va.w += v1.w;
        }
    }
    float4 sacc = make_float4(0.f, 0.f, 0.f, 0.f);

    const ushort4* up = (const ushort4*)uhat_h;
    size_t qi = ((size_t)b * 1152 + i0) * UHQ + q;

    // preload pairs 0 and 1 (4 loads in flight)
    ushort4 h0 = make_ushort4(0, 0, 0, 0), h1 = h0, g0 = h0, g1 = h0;
    if (act) {
        h0 = up[qi];           h1 = up[qi + UHQ];
        g0 = up[qi + 2 * UHQ]; g1 = up[qi + 3 * UHQ];
    }

    #pragma unroll 1
    for (int ii = 0; ii < 72; ii += 2) {
        // prefetch pair t+2 before consuming pair t
        ushort4 n0 = make_ushort4(0, 0, 0, 0), n1 = n0;
        if (act && (ii + 4 < 72)) {
            n0 = up[qi + 4 * UHQ];
            n1 = up[qi + 5 * UHQ];
        }
        qi += 2 * UHQ;

        float4 uh0 = make_float4(0.f, 0.f, 0.f, 0.f);
        float4 uh1 = make_float4(0.f, 0.f, 0.f, 0.f);
        uh0.x = bf16_to_f(h0.x); uh0.y = bf16_to_f(h0.y);
        uh0.z = bf16_to_f(h0.z); uh0.w = bf16_to_f(h0.w);
        uh1.x = bf16_to_f(h1.x); uh1.y = bf16_to_f(h1.y);
        uh1.z = bf16_to_f(h1.z); uh1.w = bf16_to_f(h1.w);
        // per-c logit: 4-lane segmented reduction (two independent chains)
        float p0 = uh0.x*va.x + uh0.y*va.y + uh0.z*va.z + uh0.w*va.w;
        float p1 = uh1.x*va.x + uh1.y*va.y + uh1.z*va.z + uh1.w*va.w;
        p0 += __shfl_xor(p0, 1);  p1 += __shfl_xor(p1, 1);
        p0 += __shfl_xor(p0, 2);  p1 += __shfl_xor(p1, 2);
        // softmax, no max-subtraction (|logit| < ~0.5); mask inactive lanes
        const float e0 = act ? __expf(p0) : 0.0f;
        const float e1 = act ? __expf(p1) : 0.0f;
        float s0v = e0, s1v = e1;
        // xor-butterfly over strides 4..32: every lane gets sum over the 10 c-groups
        s0v += __shfl_xor(s0v, 4);   s1v += __shfl_xor(s1v, 4);
        s0v += __shfl_xor(s0v, 8);   s1v += __shfl_xor(s1v, 8);
        s0v += __shfl_xor(s0v, 16);  s1v += __shfl_xor(s1v, 16);
        s0v += __shfl_xor(s0v, 32);  s1v += __shfl_xor(s1v, 32);
        const float c0 = e0 * __builtin_amdgcn_rcpf(s0v);
        const float c1 = e1 * __builtin_amdgcn_rcpf(s1v);
        sacc.x += c0 * uh0.x + c1 * uh1.x;
        sacc.y += c0 * uh0.y + c1 * uh1.y;
        sacc.z += c0 * uh0.z + c1 * uh1.z;
        sacc.w += c0 * uh0.w + c1 * uh1.w;

        h0 = g0; h1 = g1; g0 = n0; g1 = n1;
    }

    // cross-wave reduction: block's 4 waves share b -> same atomic targets
    if (wv > 0 && act) red[(wv - 1) * 40 + q] = sacc;
    __syncthreads();
    if (wv == 0 && act) {
        #pragma unroll
        for (int w = 0; w < 3; ++w) {
            const float4 r = red[w * 40 + q];
            sacc.x += r.x; sacc.y += r.y; sacc.z += r.z; sacc.w += r.w;
        }
#if defined(__HIP_DEVICE_COMPILE__)
        float* sp = sg + (size_t)b * 160 + q * 4;
        unsafeAtomicAdd(sp + 0, sacc.x);
        unsafeAtomicAdd(sp + 1, sacc.y);
        unsafeAtomicAdd(sp + 2, sacc.z);
        unsafeAtomicAdd(sp + 3, sacc.w);
#endif
    }
}

// ---------------- squash with pre-scale (final output only) ----------------
__global__ void squash_scale(const float* __restrict__ s, float* __restrict__ vout,
                             float scale)
{
    int r = blockIdx.x * 256 + threadIdx.x;
    if (r >= 512 * 10) return;
    const float* sp = s + (size_t)r * 16;
    float sv[16];
    float ns = 0.0f;
    #pragma unroll
    for (int d = 0; d < 16; ++d) {
        float x = sp[d] * scale;
        sv[d] = x;
        ns += x * x;
    }
    float sc = ns / ((1.0f + ns) * (sqrtf(ns) + 1e-8f));
    float* o = vout + (size_t)r * 16;
    #pragma unroll
    for (int d = 0; d < 16; ++d) o[d] = sv[d] * sc;
}

// ---------------- tiny-ws fallback (R3-style): thread owns (b,c) ----------------
template <int PASS>
__global__ __launch_bounds__(256, 4)
void pass_fb(const float* __restrict__ u, const float* __restrict__ W,
             const float* __restrict__ v0g, const float* __restrict__ v1g,
             float* __restrict__ s_atomic)
{
    const int t    = threadIdx.x;
    const int lane = t & 63;
    const int wv   = t >> 6;
    const int bsub = lane / 10;
    const int c    = lane - bsub * 10;
    const bool lane_ok = (bsub < 6);
    const int b    = blockIdx.y * 24 + wv * 6 + bsub;
    const bool valid = lane_ok && (b < 512);
    const int bc   = valid ? b : 511;
    const int base = lane_ok ? bsub * 10 : 0;
    const int i0   = blockIdx.x * 24;

    float v[16];
    #pragma unroll
    for (int d = 0; d < 16; ++d) v[d] = 0.0f;
    if (PASS >= 1) {
        const float* vp = v0g + ((size_t)bc * 10 + c) * 16;
        #pragma unroll
        for (int d = 0; d < 16; ++d) v[d] = vp[d];
        if (PASS >= 2) {
            const float* vq = v1g + ((size_t)bc * 10 + c) * 16;
            #pragma unroll
            for (int d = 0; d < 16; ++d) v[d] += vq[d];
        }
    }

    float s_acc[16];
    #pragma unroll
    for (int d = 0; d < 16; ++d) s_acc[d] = 0.0f;

    for (int ii = 0; ii < 24; ++ii) {
        const int i = i0 + ii;
        const float4* up = (const float4*)(u + ((size_t)bc * 1152 + i) * 8);
        const float4 ua = up[0];
        const float4 ub = up[1];
        const float* Wp = W + ((size_t)i * 10 + c) * 128;

        float h[16];
        #pragma unroll
        for (int d = 0; d < 16; ++d) {
            const float4* wp = (const float4*)(Wp + d * 8);
            h[d] = dot8(wp[0], wp[1], ua, ub);
        }

        if (PASS == 0) {
            #pragma unroll
            for (int d = 0; d < 16; ++d) s_acc[d] += h[d];
        } else {
            float lg = 0.0f;
            #pragma unroll
            for (int d = 0; d < 16; ++d) lg += h[d] * v[d];
            float lj[10];
            #pragma unroll
            for (int j = 0; j < 10; ++j) lj[j] = __shfl(lg, base + j);
            float m = lj[0];
            #pragma unroll
            for (int j = 1; j < 10; ++j) m = fmaxf(m, lj[j]);
            float sum = 0.0f;
            #pragma unroll
            for (int j = 0; j < 10; ++j) sum += __expf(lj[j] - m);
            const float coef = __expf(lg - m) / sum;
            #pragma unroll
            for (int d = 0; d < 16; ++d) s_acc[d] += coef * h[d];
        }
    }
    if (PASS == 0) {
        #pragma unroll
        for (int d = 0; d < 16; ++d) s_acc[d] *= 0.1f;
    }
    if (valid) {
#if defined(__HIP_DEVICE_COMPILE__)
        #pragma unroll
        for (int d = 0; d < 16; ++d)
            unsafeAtomicAdd(&s_atomic[((size_t)b * 10 + c) * 16 + d], s_acc[d]);
#endif
    }
}

extern "C" void kernel_launch(void* const* d_in, const int* in_sizes, int n_in,
                              void* d_out, int out_size, void* d_ws, size_t ws_size,
                              hipStream_t stream)
{
    const float* u = (const float*)d_in[0];   // [512,1152,8]
    const float* W = (const float*)d_in[1];   // [1152,10,16,8]
    float* out = (float*)d_out;               // [512,10,16]

    float* v0 = (float*)d_ws;
    float* v1 = v0 + 81920;
    float* s0 = v1 + 81920;
    float* s1 = s0 + 81920;
    float* s2 = s1 + 81920;
    float* wt = s2 + 81920;                   // 1,474,560 f32 (5.9 MB)

    const size_t head   = (size_t)5 * 81920 * sizeof(float);          // 1.64 MB
    const size_t wtsz   = (size_t)1152 * 1280 * sizeof(float);        // 5.90 MB
    const size_t uh_b16 = (size_t)512 * 1152 * 160 * 2;               // 188.7 MB

    dim3 blk(256);

    if (ws_size >= head + wtsz + uh_b16) {
        unsigned short* uhh = (unsigned short*)(wt + 1152 * 1280);
        // transpose_W also zeroes s0..s2 (61440 float4) - no separate memset
        transpose_W<<<1440, blk, 0, stream>>>((const float4*)W, (float4*)wt,
                                              (float4*)s0);
        produce_uhat_t<<<2048, blk, 0, stream>>>(u, wt, uhh, s0);
        route11<1><<<2048, blk, 0, stream>>>(uhh, s0, nullptr, s1);
        route11<2><<<2048, blk, 0, stream>>>(uhh, s0, s1, s2);
        squash_scale<<<20, blk, 0, stream>>>(s2, out, 1.0f);
    } else if (ws_size >= head + uh_b16) {
        hipMemsetAsync(s0, 0, (size_t)3 * 81920 * sizeof(float), stream);
        unsigned short* uhh = (unsigned short*)wt;   // no W_t buffer
        produce_uhat_div<<<1024, blk, 0, stream>>>(u, W, uhh, s0);
        route11<1><<<2048, blk, 0, stream>>>(uhh, s0, nullptr, s1);
        route11<2><<<2048, blk, 0, stream>>>(uhh, s0, s1, s2);
        squash_scale<<<20, blk, 0, stream>>>(s2, out, 1.0f);
    } else {
        hipMemsetAsync(s0, 0, (size_t)3 * 81920 * sizeof(float), stream);
        dim3 grid(48, 22);
        pass_fb<0><<<grid, blk, 0, stream>>>(u, W, nullptr, nullptr, s0);
        squash_scale<<<20, blk, 0, stream>>>(s0, v0, 1.0f);
        pass_fb<1><<<grid, blk, 0, stream>>>(u, W, v0, nullptr, s1);
        squash_scale<<<20, blk, 0, stream>>>(s1, v1, 1.0f);
        pass_fb<2><<<grid, blk, 0, stream>>>(u, W, v0, v1, s2);
        squash_scale<<<20, blk, 0, stream>>>(s2, out, 1.0f);
    }
}

// Round 22
// 222.149 us; speedup vs baseline: 1.2576x; 1.0057x over previous
//
#include <hip/hip_runtime.h>
#include <hip/hip_bf16.h>
#include <math.h>

// DigitCaps dynamic routing. B=512, I=1152, K=8, C=10, D=16, 3 iters.
//
// Best-known = R27 (223.4 us). Session ledger:
// R5 structure: materialize bf16 u_hat (189 MB) in ws; each routing pass
//   streams it once; softmax fully in-register.
// Producer (FROZEN, ~82us): R15 LDS cross-wave reduce; R21 u-slab in LDS
//   (128->86us); R24 cvt_pk pack. Dead-ends: ILP prefetch folded (R11),
//   forced launch_bounds spills (R7), b-oct spills (R16), sched_barrier
//   pins spilling loads (R17), b-pairs double W_t loads (R12).
// Route (~51us/pass): R14 cd-quad TLP (grid 2048 = 8 blocks/CU, HW cap);
//   R18 inline squash; R25 1-step prefetch (+3.5us/pass); R26 cross-wave
//   LDS atomic reduce (+7us/pass); R27 2-deep prefetch (+4us/pass).
//   Dead-ends: c-lane (R13), 4-wide batch (R16), global_load_lds staging
//   (R19), XCD swizzle (R22: FETCH x8 blowup).
// R28 (this round): route12 = 3-DEEP prefetch rotate (6 loads in flight).
//   Depth series: 0->1 +3.5, 1->2 +4 us/pass - not saturated. +8 VGPR
//   (~46 < 64 cliff). Falsifier: <2us gain => series converged, config
//   final next round.

#define UHQ 40          // ushort4 quads per (b,i) row (160 bf16 elems)
#define K1_CH 64        // producer i-chunks (18 i each), 4 b per wave

__device__ __forceinline__ float dot8(const float4 w0, const float4 w1,
                                      const float4 ua, const float4 ub) {
    return w0.x*ua.x + w0.y*ua.y + w0.z*ua.z + w0.w*ua.w
         + w1.x*ub.x + w1.y*ub.y + w1.z*ub.z + w1.w*ub.w;
}

__device__ __forceinline__ unsigned short bf16_rn(float x) {
    unsigned u = __float_as_uint(x);
    u += 0x7FFFu + ((u >> 16) & 1u);
    return (unsigned short)(u >> 16);
}
__device__ __forceinline__ float bf16_to_f(unsigned short h) {
    return __uint_as_float(((unsigned)h) << 16);
}

// quad-local squash: lane q holds 4 of the 16 dims of class c=q>>2; the
// 4 lanes of the quad group hold all 16. ns via shfl_xor{1,2}.
__device__ __forceinline__ float4 squash4(float4 x) {
    float ns = x.x*x.x + x.y*x.y + x.z*x.z + x.w*x.w;
    ns += __shfl_xor(ns, 1);
    ns += __shfl_xor(ns, 2);
    const float sc = ns * __builtin_amdgcn_rcpf((1.0f + ns) * (sqrtf(ns) + 1e-8f));
    return make_float4(x.x*sc, x.y*sc, x.z*sc, x.w*sc);
}

// ---------------- W transpose + s-buffer zeroing ----------------
__global__ void transpose_W(const float4* __restrict__ W4, float4* __restrict__ Wt4,
                            float4* __restrict__ zbuf)
{
    int tid = blockIdx.x * 256 + threadIdx.x;
    if (tid < 61440) zbuf[tid] = make_float4(0.f, 0.f, 0.f, 0.f);
    if (tid >= 1152 * 320) return;
    int i = tid / 320, r = tid - i * 320;
    int q = r >> 3, j = r & 7;
    Wt4[i * 320 + j * 40 + q] = W4[tid];   // read coalesced, scatter within 5 KB row
}

// ---------------- Producer (FROZEN R21+pack): u-slab LDS + cvt_pk + LDS reduce ----------------
// K1_CH 64 -> 18 i/wave, 8192 waves, grid 2048 = 8 blocks/CU (VGPR 64 tier),
// DEFAULT block mapping (no swizzle - R22). u (9.2 KB) cooperatively staged
// in LDS; pack via __float22bfloat162_rn. Waves 1-3 park pass-0 acc in LDS,
// wave 0 alone issues atomics. NO W_t prefetch (R11/R16/R17).
__global__ __launch_bounds__(256, 4)
void produce_uhat_t(const float* __restrict__ u, const float* __restrict__ Wt,
                    unsigned short* __restrict__ uhat_h, float* __restrict__ s0)
{
    const int t = threadIdx.x, lane = t & 63, wv = t >> 6;
    const int gid = blockIdx.x * 4 + wv;
    const int bq  = gid / K1_CH;          // 0..127 (same for all 4 waves of a block)
    const int b0  = bq * 4;
    const int q   = lane;
    const bool act = (q < UHQ);

    __shared__ float4 red[480];           // 3 waves x 40 lanes x 4 float4 = 7680 B
    __shared__ float4 uL[576];            // u[b0..b0+4)[iblk0..iblk0+72)[8f] = 9216 B

    const int iblk0 = (blockIdx.x & 15) * 72;   // block's i-slab start

    // cooperative stage of the block's u slab (576 float4, 256 threads)
    {
        const float4* u4 = (const float4*)u;          // [512][1152][2] float4
        #pragma unroll
        for (int idx = t; idx < 576; idx += 256) {
            const int bb = idx / 144;                 // 0..3
            const int r  = idx - bb * 144;            // 0..143
            uL[idx] = u4[((size_t)(b0 + bb) * 1152 + iblk0) * 2 + r];
        }
    }
    __syncthreads();

    float4 acc[4];
    #pragma unroll
    for (int bb = 0; bb < 4; ++bb) acc[bb] = make_float4(0.f, 0.f, 0.f, 0.f);

    for (int ii = 0; ii < 18; ++ii) {
        const int il = wv * 18 + ii;      // i - iblk0, 0..71
        const int i  = iblk0 + il;
        float4 w4[8];
        if (act) {
            const float4* wb = (const float4*)(Wt + (size_t)i * 1280);
            #pragma unroll
            for (int j = 0; j < 8; ++j) w4[j] = wb[j * 40 + q];   // 640 B contiguous
        }
        #pragma unroll
        for (int bb = 0; bb < 4; ++bb) {
            const int b = b0 + bb;
            const float4* us = &uL[(bb * 72 + il) * 2];
            const float4 ua = us[0], ub = us[1];   // broadcast ds_read, conflict-free
            if (act) {
                float4 uh;
                uh.x = dot8(w4[0], w4[1], ua, ub);
                uh.y = dot8(w4[2], w4[3], ua, ub);
                uh.z = dot8(w4[4], w4[5], ua, ub);
                uh.w = dot8(w4[6], w4[7], ua, ub);
                acc[bb].x += uh.x; acc[bb].y += uh.y;
                acc[bb].z += uh.z; acc[bb].w += uh.w;
                // RNE pack via native packed cvt (m240: intrinsic, not asm)
                __hip_bfloat162 hlo = __float22bfloat162_rn(make_float2(uh.x, uh.y));
                __hip_bfloat162 hhi = __float22bfloat162_rn(make_float2(uh.z, uh.w));
                uint2 hh;
                hh.x = *reinterpret_cast<unsigned*>(&hlo);
                hh.y = *reinterpret_cast<unsigned*>(&hhi);
                ((uint2*)uhat_h)[((size_t)b * 1152 + i) * UHQ + q] = hh;
            }
        }
    }

    // cross-wave reduction of the pass-0 partial sums
    if (wv > 0 && act) {
        float4* rp = red + ((wv - 1) * 40 + q) * 4;
        rp[0] = acc[0]; rp[1] = acc[1]; rp[2] = acc[2]; rp[3] = acc[3];
    }
    __syncthreads();
    if (wv == 0 && act) {
        #pragma unroll
        for (int w = 0; w < 3; ++w) {
            const float4* rp = red + (w * 40 + q) * 4;
            #pragma unroll
            for (int bb = 0; bb < 4; ++bb) {
                const float4 r = rp[bb];
                acc[bb].x += r.x; acc[bb].y += r.y;
                acc[bb].z += r.z; acc[bb].w += r.w;
            }
        }
#if defined(__HIP_DEVICE_COMPILE__)
        #pragma unroll
        for (int bb = 0; bb < 4; ++bb) {
            float* sp = s0 + (size_t)(b0 + bb) * 160 + q * 4;
            unsafeAtomicAdd(sp + 0, acc[bb].x);
            unsafeAtomicAdd(sp + 1, acc[bb].y);
            unsafeAtomicAdd(sp + 2, acc[bb].z);
            unsafeAtomicAdd(sp + 3, acc[bb].w);
        }
#endif
    }
}

// ---------------- Producer fallback (divergent W, no W_t buffer; R9 geometry) ----------------
__global__ __launch_bounds__(256, 4)
void produce_uhat_div(const float* __restrict__ u, const float* __restrict__ W,
                      unsigned short* __restrict__ uhat_h, float* __restrict__ s0)
{
    const int t = threadIdx.x, lane = t & 63, wv = t >> 6;
    const int gid = blockIdx.x * 4 + wv;
    const int bq  = gid / 32;
    const int ch  = gid - bq * 32;
    const int b0  = bq * 4;
    const int i0  = ch * 36;
    const int q   = lane;
    const bool act = (q < UHQ);

    float4 acc[4];
    #pragma unroll
    for (int bb = 0; bb < 4; ++bb) acc[bb] = make_float4(0.f, 0.f, 0.f, 0.f);

    for (int ii = 0; ii < 36; ++ii) {
        const int i = i0 + ii;
        float4 w4[8];
        if (act) {
            const float4* wp = (const float4*)(W + (size_t)i * 1280 + q * 32);
            #pragma unroll
            for (int j = 0; j < 8; ++j) w4[j] = wp[j];
        }
        #pragma unroll
        for (int bb = 0; bb < 4; ++bb) {
            const int b = b0 + bb;
            const float4* up = (const float4*)(u + ((size_t)b * 1152 + i) * 8);
            const float4 ua = up[0], ub = up[1];
            if (act) {
                float4 uh;
                uh.x = dot8(w4[0], w4[1], ua, ub);
                uh.y = dot8(w4[2], w4[3], ua, ub);
                uh.z = dot8(w4[4], w4[5], ua, ub);
                uh.w = dot8(w4[6], w4[7], ua, ub);
                acc[bb].x += uh.x; acc[bb].y += uh.y;
                acc[bb].z += uh.z; acc[bb].w += uh.w;
                ushort4 h;
                h.x = bf16_rn(uh.x); h.y = bf16_rn(uh.y);
                h.z = bf16_rn(uh.z); h.w = bf16_rn(uh.w);
                ((ushort4*)uhat_h)[((size_t)b * 1152 + i) * UHQ + q] = h;
            }
        }
    }
    if (act) {
#if defined(__HIP_DEVICE_COMPILE__)
        #pragma unroll
        for (int bb = 0; bb < 4; ++bb) {
            float* sp = s0 + (size_t)(b0 + bb) * 160 + q * 4;
            unsafeAtomicAdd(sp + 0, acc[bb].x);
            unsafeAtomicAdd(sp + 1, acc[bb].y);
            unsafeAtomicAdd(sp + 2, acc[bb].z);
            unsafeAtomicAdd(sp + 3, acc[bb].w);
        }
#endif
    }
}

// ---------------- Routing pass v12: 3-deep prefetch rotate + LDS atomic reduce ----------------
// Wave owns (b, i-chunk); lane q = cd-quad (40/64 active). 6 loads in
// flight (pairs t+1, t+2, t+3) while computing pair t. Block's 4 waves
// share b: waves 1-3 park sacc in LDS, wave 0 sums + issues the only
// atomics. VGPR ~46 (<64 cliff), grid 2048 = 8 blocks/CU, one round.
template <int PASS>
__global__ __launch_bounds__(256, 8)
void route12(const unsigned short* __restrict__ uhat_h,
             const float* __restrict__ s0g, const float* __restrict__ s1g,
             float* __restrict__ sg)
{
    const int t = threadIdx.x, lane = t & 63, wv = t >> 6;
    const int gid = blockIdx.x * 4 + wv;
    const int b   = gid >> 4;             // 0..511 (same for block's 4 waves)
    const int ch  = gid & 15;             // 0..15 (distinct per wave)
    const int i0  = ch * 72;
    const int q   = lane;
    const bool act = (q < UHQ);

    __shared__ float4 red[120];           // 3 waves x 40 lanes x float4 = 1920 B

    // inline squash prologue (once per wave; all lanes run the shfls)
    float4 va;
    {
        float4 x0 = make_float4(0.f, 0.f, 0.f, 0.f);
        if (act) x0 = ((const float4*)s0g)[(size_t)b * UHQ + q];
        x0.x *= 0.1f; x0.y *= 0.1f; x0.z *= 0.1f; x0.w *= 0.1f;
        va = squash4(x0);
        if (PASS == 2) {
            float4 x1 = make_float4(0.f, 0.f, 0.f, 0.f);
            if (act) x1 = ((const float4*)s1g)[(size_t)b * UHQ + q];
            const float4 v1 = squash4(x1);
            va.x += v1.x; va.y += v1.y; va.z += v1.z; va.w += v1.w;
        }
    }
    float4 sacc = make_float4(0.f, 0.f, 0.f, 0.f);

    const ushort4* up = (const ushort4*)uhat_h;
    size_t qi = ((size_t)b * 1152 + i0) * UHQ + q;

    // preload pairs 0,1,2 (6 loads in flight)
    ushort4 h0 = make_ushort4(0, 0, 0, 0), h1 = h0;
    ushort4 g0 = h0, g1 = h0, f0 = h0, f1 = h0;
    if (act) {
        h0 = up[qi];           h1 = up[qi + UHQ];
        g0 = up[qi + 2 * UHQ]; g1 = up[qi + 3 * UHQ];
        f0 = up[qi + 4 * UHQ]; f1 = up[qi + 5 * UHQ];
    }

    #pragma unroll 1
    for (int ii = 0; ii < 72; ii += 2) {
        // prefetch pair t+3 before consuming pair t
        ushort4 n0 = make_ushort4(0, 0, 0, 0), n1 = n0;
        if (act && (ii + 6 < 72)) {
            n0 = up[qi + 6 * UHQ];
            n1 = up[qi + 7 * UHQ];
        }
        qi += 2 * UHQ;

        float4 uh0 = make_float4(0.f, 0.f, 0.f, 0.f);
        float4 uh1 = make_float4(0.f, 0.f, 0.f, 0.f);
        uh0.x = bf16_to_f(h0.x); uh0.y = bf16_to_f(h0.y);
        uh0.z = bf16_to_f(h0.z); uh0.w = bf16_to_f(h0.w);
        uh1.x = bf16_to_f(h1.x); uh1.y = bf16_to_f(h1.y);
        uh1.z = bf16_to_f(h1.z); uh1.w = bf16_to_f(h1.w);
        // per-c logit: 4-lane segmented reduction (two independent chains)
        float p0 = uh0.x*va.x + uh0.y*va.y + uh0.z*va.z + uh0.w*va.w;
        float p1 = uh1.x*va.x + uh1.y*va.y + uh1.z*va.z + uh1.w*va.w;
        p0 += __shfl_xor(p0, 1);  p1 += __shfl_xor(p1, 1);
        p0 += __shfl_xor(p0, 2);  p1 += __shfl_xor(p1, 2);
        // softmax, no max-subtraction (|logit| < ~0.5); mask inactive lanes
        const float e0 = act ? __expf(p0) : 0.0f;
        const float e1 = act ? __expf(p1) : 0.0f;
        float s0v = e0, s1v = e1;
        // xor-butterfly over strides 4..32: every lane gets sum over the 10 c-groups
        s0v += __shfl_xor(s0v, 4);   s1v += __shfl_xor(s1v, 4);
        s0v += __shfl_xor(s0v, 8);   s1v += __shfl_xor(s1v, 8);
        s0v += __shfl_xor(s0v, 16);  s1v += __shfl_xor(s1v, 16);
        s0v += __shfl_xor(s0v, 32);  s1v += __shfl_xor(s1v, 32);
        const float c0 = e0 * __builtin_amdgcn_rcpf(s0v);
        const float c1 = e1 * __builtin_amdgcn_rcpf(s1v);
        sacc.x += c0 * uh0.x + c1 * uh1.x;
        sacc.y += c0 * uh0.y + c1 * uh1.y;
        sacc.z += c0 * uh0.z + c1 * uh1.z;
        sacc.w += c0 * uh0.w + c1 * uh1.w;

        h0 = g0; h1 = g1; g0 = f0; g1 = f1; f0 = n0; f1 = n1;
    }

    // cross-wave reduction: block's 4 waves share b -> same atomic targets
    if (wv > 0 && act) red[(wv - 1) * 40 + q] = sacc;
    __syncthreads();
    if (wv == 0 && act) {
        #pragma unroll
        for (int w = 0; w < 3; ++w) {
            const float4 r = red[w * 40 + q];
            sacc.x += r.x; sacc.y += r.y; sacc.z += r.z; sacc.w += r.w;
        }
#if defined(__HIP_DEVICE_COMPILE__)
        float* sp = sg + (size_t)b * 160 + q * 4;
        unsafeAtomicAdd(sp + 0, sacc.x);
        unsafeAtomicAdd(sp + 1, sacc.y);
        unsafeAtomicAdd(sp + 2, sacc.z);
        unsafeAtomicAdd(sp + 3, sacc.w);
#endif
    }
}

// ---------------- squash with pre-scale (final output only) ----------------
__global__ void squash_scale(const float* __restrict__ s, float* __restrict__ vout,
                             float scale)
{
    int r = blockIdx.x * 256 + threadIdx.x;
    if (r >= 512 * 10) return;
    const float* sp = s + (size_t)r * 16;
    float sv[16];
    float ns = 0.0f;
    #pragma unroll
    for (int d = 0; d < 16; ++d) {
        float x = sp[d] * scale;
        sv[d] = x;
        ns += x * x;
    }
    float sc = ns / ((1.0f + ns) * (sqrtf(ns) + 1e-8f));
    float* o = vout + (size_t)r * 16;
    #pragma unroll
    for (int d = 0; d < 16; ++d) o[d] = sv[d] * sc;
}

// ---------------- tiny-ws fallback (R3-style): thread owns (b,c) ----------------
template <int PASS>
__global__ __launch_bounds__(256, 4)
void pass_fb(const float* __restrict__ u, const float* __restrict__ W,
             const float* __restrict__ v0g, const float* __restrict__ v1g,
             float* __restrict__ s_atomic)
{
    const int t    = threadIdx.x;
    const int lane = t & 63;
    const int wv   = t >> 6;
    const int bsub = lane / 10;
    const int c    = lane - bsub * 10;
    const bool lane_ok = (bsub < 6);
    const int b    = blockIdx.y * 24 + wv * 6 + bsub;
    const bool valid = lane_ok && (b < 512);
    const int bc   = valid ? b : 511;
    const int base = lane_ok ? bsub * 10 : 0;
    const int i0   = blockIdx.x * 24;

    float v[16];
    #pragma unroll
    for (int d = 0; d < 16; ++d) v[d] = 0.0f;
    if (PASS >= 1) {
        const float* vp = v0g + ((size_t)bc * 10 + c) * 16;
        #pragma unroll
        for (int d = 0; d < 16; ++d) v[d] = vp[d];
        if (PASS >= 2) {
            const float* vq = v1g + ((size_t)bc * 10 + c) * 16;
            #pragma unroll
            for (int d = 0; d < 16; ++d) v[d] += vq[d];
        }
    }

    float s_acc[16];
    #pragma unroll
    for (int d = 0; d < 16; ++d) s_acc[d] = 0.0f;

    for (int ii = 0; ii < 24; ++ii) {
        const int i = i0 + ii;
        const float4* up = (const float4*)(u + ((size_t)bc * 1152 + i) * 8);
        const float4 ua = up[0];
        const float4 ub = up[1];
        const float* Wp = W + ((size_t)i * 10 + c) * 128;

        float h[16];
        #pragma unroll
        for (int d = 0; d < 16; ++d) {
            const float4* wp = (const float4*)(Wp + d * 8);
            h[d] = dot8(wp[0], wp[1], ua, ub);
        }

        if (PASS == 0) {
            #pragma unroll
            for (int d = 0; d < 16; ++d) s_acc[d] += h[d];
        } else {
            float lg = 0.0f;
            #pragma unroll
            for (int d = 0; d < 16; ++d) lg += h[d] * v[d];
            float lj[10];
            #pragma unroll
            for (int j = 0; j < 10; ++j) lj[j] = __shfl(lg, base + j);
            float m = lj[0];
            #pragma unroll
            for (int j = 1; j < 10; ++j) m = fmaxf(m, lj[j]);
            float sum = 0.0f;
            #pragma unroll
            for (int j = 0; j < 10; ++j) sum += __expf(lj[j] - m);
            const float coef = __expf(lg - m) / sum;
            #pragma unroll
            for (int d = 0; d < 16; ++d) s_acc[d] += coef * h[d];
        }
    }
    if (PASS == 0) {
        #pragma unroll
        for (int d = 0; d < 16; ++d) s_acc[d] *= 0.1f;
    }
    if (valid) {
#if defined(__HIP_DEVICE_COMPILE__)
        #pragma unroll
        for (int d = 0; d < 16; ++d)
            unsafeAtomicAdd(&s_atomic[((size_t)b * 10 + c) * 16 + d], s_acc[d]);
#endif
    }
}

extern "C" void kernel_launch(void* const* d_in, const int* in_sizes, int n_in,
                              void* d_out, int out_size, void* d_ws, size_t ws_size,
                              hipStream_t stream)
{
    const float* u = (const float*)d_in[0];   // [512,1152,8]
    const float* W = (const float*)d_in[1];   // [1152,10,16,8]
    float* out = (float*)d_out;               // [512,10,16]

    float* v0 = (float*)d_ws;
    float* v1 = v0 + 81920;
    float* s0 = v1 + 81920;
    float* s1 = s0 + 81920;
    float* s2 = s1 + 81920;
    float* wt = s2 + 81920;                   // 1,474,560 f32 (5.9 MB)

    const size_t head   = (size_t)5 * 81920 * sizeof(float);          // 1.64 MB
    const size_t wtsz   = (size_t)1152 * 1280 * sizeof(float);        // 5.90 MB
    const size_t uh_b16 = (size_t)512 * 1152 * 160 * 2;               // 188.7 MB

    dim3 blk(256);

    if (ws_size >= head + wtsz + uh_b16) {
        unsigned short* uhh = (unsigned short*)(wt + 1152 * 1280);
        // transpose_W also zeroes s0..s2 (61440 float4) - no separate memset
        transpose_W<<<1440, blk, 0, stream>>>((const float4*)W, (float4*)wt,
                                              (float4*)s0);
        produce_uhat_t<<<2048, blk, 0, stream>>>(u, wt, uhh, s0);
        route12<1><<<2048, blk, 0, stream>>>(uhh, s0, nullptr, s1);
        route12<2><<<2048, blk, 0, stream>>>(uhh, s0, s1, s2);
        squash_scale<<<20, blk, 0, stream>>>(s2, out, 1.0f);
    } else if (ws_size >= head + uh_b16) {
        hipMemsetAsync(s0, 0, (size_t)3 * 81920 * sizeof(float), stream);
        unsigned short* uhh = (unsigned short*)wt;   // no W_t buffer
        produce_uhat_div<<<1024, blk, 0, stream>>>(u, W, uhh, s0);
        route12<1><<<2048, blk, 0, stream>>>(uhh, s0, nullptr, s1);
        route12<2><<<2048, blk, 0, stream>>>(uhh, s0, s1, s2);
        squash_scale<<<20, blk, 0, stream>>>(s2, out, 1.0f);
    } else {
        hipMemsetAsync(s0, 0, (size_t)3 * 81920 * sizeof(float), stream);
        dim3 grid(48, 22);
        pass_fb<0><<<grid, blk, 0, stream>>>(u, W, nullptr, nullptr, s0);
        squash_scale<<<20, blk, 0, stream>>>(s0, v0, 1.0f);
        pass_fb<1><<<grid, blk, 0, stream>>>(u, W, v0, nullptr, s1);
        squash_scale<<<20, blk, 0, stream>>>(s1, v1, 1.0f);
        pass_fb<2><<<grid, blk, 0, stream>>>(u, W, v0, v1, s2);
        squash_scale<<<20, blk, 0, stream>>>(s2, out, 1.0f);
    }
}